// Round 6
// baseline (4675.710 us; speedup 1.0000x reference)
//
#include <hip/hip_runtime.h>

typedef unsigned short u16;
typedef unsigned int u32;
typedef __attribute__((ext_vector_type(8))) short s16x8;
typedef __attribute__((ext_vector_type(8))) unsigned short u16x8;
typedef __attribute__((ext_vector_type(4))) float f32x4;
typedef __attribute__((ext_vector_type(4))) unsigned int u32x4;

__device__ __forceinline__ u16 f2bf(float f) {
    u32 u = __float_as_uint(f);
    u32 r = (u + 0x7fffu + ((u >> 16) & 1u)) >> 16;
    return (u16)r;
}
__device__ __forceinline__ float bf2f(u16 u) { return __uint_as_float(((u32)u) << 16); }
__device__ __forceinline__ float bflo(u32 u) { return __uint_as_float(u << 16); }
__device__ __forceinline__ float bfhi(u32 u) { return __uint_as_float(u & 0xffff0000u); }
__device__ __forceinline__ float gelu_exact(float v) {
    return 0.5f * v * (1.0f + erff(v * 0.70710678118654752f));
}

// async global -> LDS, 16B per lane. LDS dest = wave-uniform base + lane*16.
__device__ __forceinline__ void gload16(const void* g, void* l) {
    __builtin_amdgcn_global_load_lds(
        (const __attribute__((address_space(1))) u32*)g,
        (__attribute__((address_space(3))) u32*)l, 16, 0, 0);
}

// ---------------- fp32 -> bf16 convert: 5 weight tensors in one launch ----------------
__global__ __launch_bounds__(256) void k_cvt5(const float* __restrict__ s0, u16* __restrict__ d0,
                                              const float* __restrict__ s1, u16* __restrict__ d1,
                                              const float* __restrict__ s2, u16* __restrict__ d2,
                                              const float* __restrict__ s3, u16* __restrict__ d3,
                                              const float* __restrict__ s4, u16* __restrict__ d4) {
    int i = blockIdx.x * 256 + threadIdx.x;
    const float* s; u16* d; int off;
    if (i < 786432)       { s = s0; d = d0; off = i; }
    else if (i < 1048576) { s = s1; d = d1; off = i - 786432; }
    else if (i < 1572864) { s = s2; d = d2; off = i - 1048576; }
    else if (i < 2097152) { s = s3; d = d3; off = i - 1572864; }
    else                  { s = s4; d = d4; off = i - 2097152; }
    float4 v = *(const float4*)(s + (size_t)off * 4);
    u16 o0 = f2bf(v.x), o1 = f2bf(v.y), o2 = f2bf(v.z), o3 = f2bf(v.w);
    uint2 o; o.x = (u32)o0 | ((u32)o1 << 16); o.y = (u32)o2 | ((u32)o3 << 16);
    *(uint2*)(d + (size_t)off * 4) = o;
}

// ---------------- qw = pool_w^T . pool_q  (512 outputs, f32) ----------------
__global__ __launch_bounds__(256) void k_poolq(const float* __restrict__ pq,
                                               const float* __restrict__ W,
                                               float* __restrict__ qw) {
    int d = blockIdx.x * 256 + threadIdx.x;
    float s = 0.f;
    for (int e = 0; e < 512; ++e) s += pq[e] * W[(size_t)e * 512 + d];
    qw[d] = s;
}

// ---------------- embed + ln1(l=0) fused: one block per sample ----------------
__global__ __launch_bounds__(256) void k_embed_ln(const float* __restrict__ x,
                                                  const float* __restrict__ be,
                                                  const float* __restrict__ w,
                                                  const float* __restrict__ b,
                                                  u16* __restrict__ Xb,
                                                  u16* __restrict__ Hb) {
    __shared__ u16 ld[4][512];
    int s = blockIdx.x;
    int tid = threadIdx.x;
    const float* xs = x + (size_t)s * 2048;
#pragma unroll
    for (int i = 0; i < 2; ++i) {
        int d = tid + i * 256;
        float4 v = *(const float4*)(xs + d * 4);
        ld[0][d] = f2bf(v.x + be[d]);
        ld[1][d] = f2bf(v.y + be[512 + d]);
        ld[2][d] = f2bf(v.z + be[1024 + d]);
        ld[3][d] = f2bf(v.w + be[1536 + d]);
    }
    __syncthreads();
    int t = tid >> 6, lane = tid & 63;
    u16x8 raw = *(const u16x8*)(&ld[t][lane * 8]);
    *(u16x8*)(Xb + ((size_t)s * 4 + t) * 512 + lane * 8) = raw;
    float a[8];
#pragma unroll
    for (int j = 0; j < 8; ++j) a[j] = bf2f(raw[j]);
    float s1 = 0.f, s2 = 0.f;
#pragma unroll
    for (int j = 0; j < 8; ++j) { s1 += a[j]; s2 += a[j] * a[j]; }
#pragma unroll
    for (int d = 1; d < 64; d <<= 1) { s1 += __shfl_xor(s1, d); s2 += __shfl_xor(s2, d); }
    float mean = s1 * (1.0f / 512.0f);
    float var  = s2 * (1.0f / 512.0f) - mean * mean;
    float rstd = rsqrtf(var + 1e-5f);
    float4 w0 = *(const float4*)(w + lane * 8);
    float4 w1 = *(const float4*)(w + lane * 8 + 4);
    float4 b0 = *(const float4*)(b + lane * 8);
    float4 b1 = *(const float4*)(b + lane * 8 + 4);
    float wv[8] = {w0.x, w0.y, w0.z, w0.w, w1.x, w1.y, w1.z, w1.w};
    float bv[8] = {b0.x, b0.y, b0.z, b0.w, b1.x, b1.y, b1.z, b1.w};
    u16x8 o;
#pragma unroll
    for (int j = 0; j < 8; ++j) o[j] = f2bf((a[j] - mean) * rstd * wv[j] + bv[j]);
    *(u16x8*)(Hb + ((size_t)s * 4 + t) * 512 + lane * 8) = o;
}

// ---------------- GEMM: persistent 8-phase (cross-tile pipelined) ----------------
// 256x256 tile, BK=64, 8 waves, 2x64KB LDS bufs, persistent blocks.
// XCD-aware panel-sharing tile schedule (verified R2). RESID: bf16 RMW of Xb.
// BOUNCE+NT (QKV/FFN1, verified R1/R5): per-wave 2KB LDS bounce -> full-line
// NT stores. LNF (implies RESID, ncols==512, TN==2): supertile order
// (both by-tiles of a bx consecutively) + fused LayerNorm in the epilogue:
// half0 accumulates row partials (sum,sumsq of bf16-rounded resid values) in
// LDS; half1 completes stats, writes Hb = ln(X)*w+b (cols 256-511 from regs,
// cols 0-255 re-read from L2-hot Xb). Kills the separate k_ln pass.
template <bool BIAS, bool GELU_, bool RESID, bool BOUNCE, bool NT, bool LNF>
__global__ __launch_bounds__(512, 2) void k_gemm256(const u16* __restrict__ A,
                                                    const u16* __restrict__ W,
                                                    const float* __restrict__ bias,
                                                    u16* __restrict__ Cb,
                                                    u16* __restrict__ Xbres,
                                                    const float* __restrict__ lnw,
                                                    const float* __restrict__ lnb,
                                                    u16* __restrict__ Hout,
                                                    int K, int ncols, int TN, int T) {
    __shared__ __align__(16) u16 lds[2 * 32768];
    __shared__ __align__(16) u16 bounce[8192];  // 16 KB: bounce / LN partials
    int tid = threadIdx.x;
    int lane = tid & 63;
    int wid = tid >> 6;
    int G = gridDim.x, b = blockIdx.x;
    int startTi, ue = 0, ustep = 0, endT = 0, stepT = 0;
    if (LNF) {
        int U = T >> 1;
        int us;
        if ((G & 7) == 0) {
            int xcd = b & 7, nxb = G >> 3, j = b >> 3;
            us = (int)(((long long)xcd * U) >> 3) + j;
            ue = (int)(((long long)(xcd + 1) * U) >> 3);
            ustep = nxb;
        } else {
            us = (int)(((long long)b * U) / G);
            ue = (int)(((long long)(b + 1) * U) / G);
            ustep = 1;
        }
        if (us >= ue) return;
        startTi = us * 2;
    } else {
        int st;
        if ((G & 7) == 0) {
            int xcd = b & 7, nxb = G >> 3, j = b >> 3;
            st = (int)(((long long)xcd * T) >> 3) + j;
            endT = (int)(((long long)(xcd + 1) * T) >> 3);
            stepT = nxb;
        } else {
            st = (int)(((long long)b * T) / G);
            endT = (int)(((long long)(b + 1) * T) / G);
            stepT = 1;
        }
        if (st >= endT) return;
        startTi = st;
    }
    auto nextOf = [&](int ti) -> int {
        if (LNF) {
            if (!(ti & 1)) return ti + 1;
            int u = (ti >> 1) + ustep;
            return u < ue ? u * 2 : -1;
        } else {
            int n = ti + stepT;
            return n < endT ? n : -1;
        }
    };
    int NS = K >> 6;   // K-steps of 64 (K in {512,1024})
    int mgrp = wid >> 2, ngrp = wid & 3;

    f32x4 acc[8][4];
#pragma unroll
    for (int i = 0; i < 8; ++i)
#pragma unroll
        for (int j = 0; j < 4; ++j) acc[i][j] = (f32x4){0.f, 0.f, 0.f, 0.f};

    int srow = tid >> 3;
    int sel  = (((tid & 7) * 16) ^ ((srow & 7) << 4)) >> 1;
    size_t K64 = (size_t)K * 64;
    char* ldsB = (char*)lds;
    int wdst = wid * 1024;

    const u16 *cA0, *cA1, *cB0, *cB1, *nA0, *nA1, *nB0, *nB1;
    int cm0, cn0, nm0, nn0;
    auto tilePtrs = [&](int ti, const u16*& a0, const u16*& a1,
                        const u16*& b0, const u16*& b1, int& m0o, int& n0o) {
        int bx = ti / TN, by = ti - bx * TN;
        int m0 = bx * 256, n0 = by * 256;
        a0 = A + (size_t)(m0 + srow) * K + sel;
        a1 = A + (size_t)(m0 + 128 + srow) * K + sel;
        b0 = W + (size_t)(n0 + srow) * K + sel;
        b1 = W + (size_t)(n0 + 128 + srow) * K + sel;
        m0o = m0; n0o = n0;
    };

    auto S_Aq12 = [&](const u16* a0, const u16* a1, int s) {
        char* d = ldsB + (s & 1) * 65536 + wdst;
        gload16(a0 + (size_t)s * 64, d);
        gload16(a1 + (size_t)s * 64, d + 16384);
    };
    auto S_Aq34 = [&](const u16* a0, const u16* a1, int s) {
        char* d = ldsB + (s & 1) * 65536 + 8192 + wdst;
        gload16(a0 + K64 + (size_t)s * 64, d);
        gload16(a1 + K64 + (size_t)s * 64, d + 16384);
    };
    auto S_Blo = [&](const u16* b0, int s) {
        char* d = ldsB + (s & 1) * 65536 + 32768 + wdst;
        gload16(b0 + (size_t)s * 64, d);
        gload16(b0 + K64 + (size_t)s * 64, d + 8192);
    };
    auto S_Bhi = [&](const u16* b1, int s) {
        char* d = ldsB + (s & 1) * 65536 + 49152 + wdst;
        gload16(b1 + (size_t)s * 64, d);
        gload16(b1 + K64 + (size_t)s * 64, d + 8192);
    };

    int arow = mgrp * 128 + (lane & 15);
    int brow = ngrp * 64 + (lane & 15);
    int sub = (lane >> 4) << 4;
    int amask = ((arow & 7) << 4), bmask = ((brow & 7) << 4);
    int aoff0 = arow * 128 + (sub ^ amask);
    int boff0 = 32768 + brow * 128 + (sub ^ bmask);
    int aoff1 = arow * 128 + ((sub | 64) ^ amask);
    int boff1 = 32768 + brow * 128 + ((sub | 64) ^ bmask);

    if (LNF) {  // zero LN-partial region (8 KB = 512 float4, 512 threads)
        *((float4*)bounce + tid) = (float4){0.f, 0.f, 0.f, 0.f};
    }

    tilePtrs(startTi, cA0, cA1, cB0, cB1, cm0, cn0);
    S_Blo(cB0, 0); S_Bhi(cB1, 0); S_Aq12(cA0, cA1, 0); S_Aq34(cA0, cA1, 0);
    S_Blo(cB0, 1); S_Bhi(cB1, 1); S_Aq12(cA0, cA1, 1);
    asm volatile("s_waitcnt vmcnt(6)" ::: "memory");
    __builtin_amdgcn_s_barrier();

    int ti = startTi;
    while (true) {
        int tnext = nextOf(ti);
        bool hasNext = tnext >= 0;
        if (hasNext) tilePtrs(tnext, nA0, nA1, nB0, nB1, nm0, nn0);

        s16x8 bfr[4][2];
        for (int s = 0; s < NS; ++s) {
            const char* sb = ldsB + (s & 1) * 65536;
            int st = s + 1, st2 = s + 2;
            bool n1 = st < NS, n2 = st2 < NS;
            // ---------- phase 1 ----------
            s16x8 af[2][2];
#pragma unroll
            for (int ni = 0; ni < 4; ++ni) {
                bfr[ni][0] = *(const s16x8*)(sb + boff0 + ni * 2048);
                bfr[ni][1] = *(const s16x8*)(sb + boff1 + ni * 2048);
            }
            af[0][0] = *(const s16x8*)(sb + aoff0);
            af[0][1] = *(const s16x8*)(sb + aoff1);
            af[1][0] = *(const s16x8*)(sb + aoff0 + 2048);
            af[1][1] = *(const s16x8*)(sb + aoff1 + 2048);
            if (n1) S_Aq34(cA0, cA1, st); else if (hasNext) S_Aq34(nA0, nA1, st - NS);
            __builtin_amdgcn_s_barrier();
            __builtin_amdgcn_s_setprio(1);
#pragma unroll
            for (int mj = 0; mj < 2; ++mj)
#pragma unroll
                for (int ni = 0; ni < 4; ++ni) {
                    acc[mj][ni] = __builtin_amdgcn_mfma_f32_16x16x32_bf16(bfr[ni][0], af[mj][0], acc[mj][ni], 0, 0, 0);
                    acc[mj][ni] = __builtin_amdgcn_mfma_f32_16x16x32_bf16(bfr[ni][1], af[mj][1], acc[mj][ni], 0, 0, 0);
                }
            __builtin_amdgcn_s_setprio(0);
            __builtin_amdgcn_s_barrier();
            // ---------- phase 2 ----------
#pragma unroll
            for (int mj = 0; mj < 2; ++mj) {
                af[mj][0] = *(const s16x8*)(sb + aoff0 + (2 + mj) * 2048);
                af[mj][1] = *(const s16x8*)(sb + aoff1 + (2 + mj) * 2048);
            }
            if (n2) S_Blo(cB0, st2); else if (hasNext) S_Blo(nB0, st2 - NS);
            __builtin_amdgcn_s_barrier();
            __builtin_amdgcn_s_setprio(1);
#pragma unroll
            for (int mj = 0; mj < 2; ++mj)
#pragma unroll
                for (int ni = 0; ni < 4; ++ni) {
                    acc[2 + mj][ni] = __builtin_amdgcn_mfma_f32_16x16x32_bf16(bfr[ni][0], af[mj][0], acc[2 + mj][ni], 0, 0, 0);
                    acc[2 + mj][ni] = __builtin_amdgcn_mfma_f32_16x16x32_bf16(bfr[ni][1], af[mj][1], acc[2 + mj][ni], 0, 0, 0);
                }
            __builtin_amdgcn_s_setprio(0);
            __builtin_amdgcn_s_barrier();
            // ---------- phase 3 ----------
#pragma unroll
            for (int mj = 0; mj < 2; ++mj) {
                af[mj][0] = *(const s16x8*)(sb + aoff0 + (4 + mj) * 2048);
                af[mj][1] = *(const s16x8*)(sb + aoff1 + (4 + mj) * 2048);
            }
            if (n2) S_Bhi(cB1, st2); else if (hasNext) S_Bhi(nB1, st2 - NS);
            __builtin_amdgcn_s_barrier();
            __builtin_amdgcn_s_setprio(1);
#pragma unroll
            for (int mj = 0; mj < 2; ++mj)
#pragma unroll
                for (int ni = 0; ni < 4; ++ni) {
                    acc[4 + mj][ni] = __builtin_amdgcn_mfma_f32_16x16x32_bf16(bfr[ni][0], af[mj][0], acc[4 + mj][ni], 0, 0, 0);
                    acc[4 + mj][ni] = __builtin_amdgcn_mfma_f32_16x16x32_bf16(bfr[ni][1], af[mj][1], acc[4 + mj][ni], 0, 0, 0);
                }
            __builtin_amdgcn_s_setprio(0);
            __builtin_amdgcn_s_barrier();
            // ---------- phase 4 ----------
#pragma unroll
            for (int mj = 0; mj < 2; ++mj) {
                af[mj][0] = *(const s16x8*)(sb + aoff0 + (6 + mj) * 2048);
                af[mj][1] = *(const s16x8*)(sb + aoff1 + (6 + mj) * 2048);
            }
            if (n2) S_Aq12(cA0, cA1, st2); else if (hasNext) S_Aq12(nA0, nA1, st2 - NS);
            __builtin_amdgcn_s_barrier();
            __builtin_amdgcn_s_setprio(1);
#pragma unroll
            for (int mj = 0; mj < 2; ++mj)
#pragma unroll
                for (int ni = 0; ni < 4; ++ni) {
                    acc[6 + mj][ni] = __builtin_amdgcn_mfma_f32_16x16x32_bf16(bfr[ni][0], af[mj][0], acc[6 + mj][ni], 0, 0, 0);
                    acc[6 + mj][ni] = __builtin_amdgcn_mfma_f32_16x16x32_bf16(bfr[ni][1], af[mj][1], acc[6 + mj][ni], 0, 0, 0);
                }
            __builtin_amdgcn_s_setprio(0);
            bool staged24 = n2 || hasNext;
            bool last = (s == NS - 1) && !hasNext;
            if (!last) {
                if (staged24) asm volatile("s_waitcnt vmcnt(6)" ::: "memory");
                else          asm volatile("s_waitcnt vmcnt(0)" ::: "memory");
                __builtin_amdgcn_s_barrier();
            }
        }

        // ---- epilogue for tile ti ----
        int r_lane = lane & 15, cg = lane >> 4;
        float4 bb[4];
        if (BIAS) {
#pragma unroll
            for (int ni = 0; ni < 4; ++ni)
                bb[ni] = *(const float4*)(bias + cn0 + ngrp * 64 + ni * 16 + cg * 4);
        }
        if (LNF) {
            float* pS = (float*)bounce;     // [4 ngrp][256 rows][2]
            bool half1 = (ti & 1) != 0;
#pragma unroll
            for (int mi = 0; mi < 8; ++mi) {
                int lrow = mgrp * 128 + mi * 16 + r_lane;
                int row = cm0 + lrow;
                float s1 = 0.f, s2 = 0.f;
#pragma unroll
                for (int ni = 0; ni < 4; ++ni) {
                    int c = cn0 + ngrp * 64 + ni * 16 + cg * 4;
                    f32x4 v = acc[mi][ni];
                    if (BIAS) { v[0] += bb[ni].x; v[1] += bb[ni].y; v[2] += bb[ni].z; v[3] += bb[ni].w; }
                    u16* px = Xbres + (size_t)row * 512 + c;
                    uint2 xv = *(uint2*)px;
                    float x0 = bflo(xv.x) + v[0];
                    float x1 = bfhi(xv.x) + v[1];
                    float x2 = bflo(xv.y) + v[2];
                    float x3 = bfhi(xv.y) + v[3];
                    uint2 o;
                    o.x = (u32)f2bf(x0) | ((u32)f2bf(x1) << 16);
                    o.y = (u32)f2bf(x2) | ((u32)f2bf(x3) << 16);
                    *(uint2*)px = o;
                    float r0 = bflo(o.x), r1 = bfhi(o.x), r2 = bflo(o.y), r3 = bfhi(o.y);
                    s1 += r0 + r1 + r2 + r3;
                    s2 += r0 * r0 + r1 * r1 + r2 * r2 + r3 * r3;
                    if (half1) acc[mi][ni] = (f32x4){r0, r1, r2, r3};
                    else       acc[mi][ni] = (f32x4){0.f, 0.f, 0.f, 0.f};
                }
                s1 += __shfl_xor(s1, 16); s2 += __shfl_xor(s2, 16);
                s1 += __shfl_xor(s1, 32); s2 += __shfl_xor(s2, 32);
                if (cg == 0) {
                    float* p = pS + ((ngrp << 8) + lrow) * 2;
                    p[0] += s1; p[1] += s2;
                }
            }
            if (half1) {
                __syncthreads();
                float mean[8], rstd[8];
#pragma unroll
                for (int mi = 0; mi < 8; ++mi) {
                    int lrow = mgrp * 128 + mi * 16 + r_lane;
                    float t1 = 0.f, t2 = 0.f;
#pragma unroll
                    for (int g = 0; g < 4; ++g) {
                        float2 pv = *(float2*)(pS + ((g << 8) + lrow) * 2);
                        t1 += pv.x; t2 += pv.y;
                    }
                    float m = t1 * (1.0f / 512.0f);
                    mean[mi] = m;
                    rstd[mi] = rsqrtf(t2 * (1.0f / 512.0f) - m * m + 1e-5f);
                }
                // Hb cols 256-511 from registers (this half's values)
#pragma unroll
                for (int mi = 0; mi < 8; ++mi) {
                    int row = cm0 + mgrp * 128 + mi * 16 + r_lane;
#pragma unroll
                    for (int ni = 0; ni < 4; ++ni) {
                        int c = 256 + ngrp * 64 + ni * 16 + cg * 4;
                        float4 wv = *(const float4*)(lnw + c);
                        float4 bv = *(const float4*)(lnb + c);
                        f32x4 v = acc[mi][ni];
                        uint2 o;
                        o.x = (u32)f2bf((v[0] - mean[mi]) * rstd[mi] * wv.x + bv.x)
                            | ((u32)f2bf((v[1] - mean[mi]) * rstd[mi] * wv.y + bv.y) << 16);
                        o.y = (u32)f2bf((v[2] - mean[mi]) * rstd[mi] * wv.z + bv.z)
                            | ((u32)f2bf((v[3] - mean[mi]) * rstd[mi] * wv.w + bv.w) << 16);
                        *(uint2*)(Hout + (size_t)row * 512 + c) = o;
                        acc[mi][ni] = (f32x4){0.f, 0.f, 0.f, 0.f};
                    }
                }
                // Hb cols 0-255: re-read own L2-hot Xb half
#pragma unroll
                for (int mi = 0; mi < 8; ++mi) {
                    int row = cm0 + mgrp * 128 + mi * 16 + r_lane;
#pragma unroll
                    for (int ni = 0; ni < 4; ++ni) {
                        int c = ngrp * 64 + ni * 16 + cg * 4;
                        uint2 xv = *(const uint2*)(Xbres + (size_t)row * 512 + c);
                        float4 wv = *(const float4*)(lnw + c);
                        float4 bv = *(const float4*)(lnb + c);
                        float r0 = bflo(xv.x), r1 = bfhi(xv.x), r2 = bflo(xv.y), r3 = bfhi(xv.y);
                        uint2 o;
                        o.x = (u32)f2bf((r0 - mean[mi]) * rstd[mi] * wv.x + bv.x)
                            | ((u32)f2bf((r1 - mean[mi]) * rstd[mi] * wv.y + bv.y) << 16);
                        o.y = (u32)f2bf((r2 - mean[mi]) * rstd[mi] * wv.z + bv.z)
                            | ((u32)f2bf((r3 - mean[mi]) * rstd[mi] * wv.w + bv.w) << 16);
                        *(uint2*)(Hout + (size_t)row * 512 + c) = o;
                    }
                }
                __syncthreads();
                if (cg == 0) {
#pragma unroll
                    for (int mi = 0; mi < 8; ++mi) {
                        int lrow = mgrp * 128 + mi * 16 + r_lane;
                        float* p = pS + ((ngrp << 8) + lrow) * 2;
                        p[0] = 0.f; p[1] = 0.f;
                    }
                }
            }
        } else if (BOUNCE) {
            u16* bw = bounce + wid * 1024;
            int qrow = lane >> 3, kc = lane & 7;
#pragma unroll
            for (int mi = 0; mi < 8; ++mi) {
                int rowbase = cm0 + mgrp * 128 + mi * 16;
#pragma unroll
                for (int ni = 0; ni < 4; ++ni) {
                    f32x4 v = acc[mi][ni];
                    if (BIAS) { v[0] += bb[ni].x; v[1] += bb[ni].y; v[2] += bb[ni].z; v[3] += bb[ni].w; }
                    if (GELU_) {
#pragma unroll
                        for (int j = 0; j < 4; ++j) v[j] = gelu_exact(v[j]);
                    }
                    uint2 o;
                    o.x = (u32)f2bf(v[0]) | ((u32)f2bf(v[1]) << 16);
                    o.y = (u32)f2bf(v[2]) | ((u32)f2bf(v[3]) << 16);
                    int slot = (4 * ni + cg) ^ (r_lane & 14);
                    *(uint2*)(bw + r_lane * 64 + slot * 4) = o;
                    acc[mi][ni] = (f32x4){0.f, 0.f, 0.f, 0.f};
                }
                asm volatile("s_waitcnt lgkmcnt(0)" ::: "memory");
#pragma unroll
                for (int h = 0; h < 2; ++h) {
                    int rd = h * 8 + qrow;
                    int e = (2 * kc) ^ (rd & 14);
                    u32x4 t = *(const u32x4*)(bw + rd * 64 + e * 4);
                    int row = rowbase + rd;
                    int c2 = cn0 + ngrp * 64 + kc * 8;
                    u16* dst = Cb + (size_t)row * ncols + c2;
                    if (NT) __builtin_nontemporal_store(t, (u32x4*)dst);
                    else    *(u32x4*)dst = t;
                }
                asm volatile("s_waitcnt lgkmcnt(0)" ::: "memory");
            }
        } else {
#pragma unroll
            for (int mi = 0; mi < 8; ++mi) {
                int row = cm0 + mgrp * 128 + mi * 16 + r_lane;
#pragma unroll
                for (int ni = 0; ni < 4; ++ni) {
                    int c = cn0 + ngrp * 64 + ni * 16 + cg * 4;
                    f32x4 v = acc[mi][ni];
                    if (BIAS) { v[0] += bb[ni].x; v[1] += bb[ni].y; v[2] += bb[ni].z; v[3] += bb[ni].w; }
                    if (GELU_) {
#pragma unroll
                        for (int j = 0; j < 4; ++j) v[j] = gelu_exact(v[j]);
                    }
                    if (RESID) {
                        u16* px = Xbres + (size_t)row * 512 + c;
                        uint2 xv = *(uint2*)px;
                        float x0 = bflo(xv.x) + v[0];
                        float x1 = bfhi(xv.x) + v[1];
                        float x2 = bflo(xv.y) + v[2];
                        float x3 = bfhi(xv.y) + v[3];
                        uint2 o;
                        o.x = (u32)f2bf(x0) | ((u32)f2bf(x1) << 16);
                        o.y = (u32)f2bf(x2) | ((u32)f2bf(x3) << 16);
                        *(uint2*)px = o;
                    } else {
                        u32 lo = (u32)f2bf(v[0]) | ((u32)f2bf(v[1]) << 16);
                        u32 hi = (u32)f2bf(v[2]) | ((u32)f2bf(v[3]) << 16);
                        uint2 o; o.x = lo; o.y = hi;
                        *(uint2*)(Cb + (size_t)row * ncols + c) = o;
                    }
                    acc[mi][ni] = (f32x4){0.f, 0.f, 0.f, 0.f};
                }
            }
        }
        if (!hasNext) break;
        cA0 = nA0; cA1 = nA1; cB0 = nB0; cB1 = nB1; cm0 = nm0; cn0 = nn0;
        ti = tnext;
    }
}

// ---------------- attention: T=4, per (sample, head) per wave ----------------
__global__ __launch_bounds__(256) void k_attn(const u16* __restrict__ QKV, u16* __restrict__ O) {
    int task = blockIdx.x * 4 + (threadIdx.x >> 6);
    int lane = threadIdx.x & 63;
    int s = task >> 2, h = task & 3;
    const u16* base = QKV + (size_t)s * 4 * 1536 + h * 128;
    float q[4][2], k[4][2], v[4][2];
#pragma unroll
    for (int t = 0; t < 4; ++t) {
        const u16* row = base + t * 1536;
        u32 uq = *(const u32*)(row + lane * 2);
        u32 uk = *(const u32*)(row + 512 + lane * 2);
        u32 uv = *(const u32*)(row + 1024 + lane * 2);
        q[t][0] = bflo(uq); q[t][1] = bfhi(uq);
        k[t][0] = bflo(uk); k[t][1] = bfhi(uk);
        v[t][0] = bflo(uv); v[t][1] = bfhi(uv);
    }
    float sc[4][4];
#pragma unroll
    for (int i = 0; i < 4; ++i)
#pragma unroll
        for (int j = 0; j < 4; ++j) {
            float p = q[i][0] * k[j][0] + q[i][1] * k[j][1];
#pragma unroll
            for (int d = 1; d < 64; d <<= 1) p += __shfl_xor(p, d);
            sc[i][j] = p * 0.08838834764831845f;  // 1/sqrt(128)
        }
    float o[4][2];
#pragma unroll
    for (int i = 0; i < 4; ++i) {
        float mx = fmaxf(fmaxf(sc[i][0], sc[i][1]), fmaxf(sc[i][2], sc[i][3]));
        float e0 = expf(sc[i][0] - mx), e1 = expf(sc[i][1] - mx);
        float e2 = expf(sc[i][2] - mx), e3 = expf(sc[i][3] - mx);
        float inv = 1.0f / (e0 + e1 + e2 + e3);
        float a0 = e0 * inv, a1 = e1 * inv, a2 = e2 * inv, a3 = e3 * inv;
        o[i][0] = a0 * v[0][0] + a1 * v[1][0] + a2 * v[2][0] + a3 * v[3][0];
        o[i][1] = a0 * v[0][1] + a1 * v[1][1] + a2 * v[2][1] + a3 * v[3][1];
    }
#pragma unroll
    for (int i = 0; i < 4; ++i) {
        u32 pk = (u32)f2bf(o[i][0]) | ((u32)f2bf(o[i][1]) << 16);
        *(u32*)(O + ((size_t)s * 4 + i) * 512 + h * 128 + lane * 2) = pk;
    }
}

// ---------------- pooling: score via qw, z, out-LN -> Zb bf16 ; wave per sample ----------------
__global__ __launch_bounds__(256) void k_pool(const u16* __restrict__ Xb, const float* __restrict__ qw,
                                              const float* __restrict__ olnw, const float* __restrict__ olnb,
                                              u16* __restrict__ Zb) {
    int s = blockIdx.x * 4 + (threadIdx.x >> 6);
    int lane = threadIdx.x & 63;
    float4 q0 = *(const float4*)(qw + lane * 8);
    float4 q1 = *(const float4*)(qw + lane * 8 + 4);
    float qv[8] = {q0.x, q0.y, q0.z, q0.w, q1.x, q1.y, q1.z, q1.w};
    u16x8 xr[4];
    float dot[4];
#pragma unroll
    for (int t = 0; t < 4; ++t) {
        xr[t] = *(const u16x8*)(Xb + ((size_t)s * 4 + t) * 512 + lane * 8);
        float p = 0.f;
#pragma unroll
        for (int j = 0; j < 8; ++j) p += qv[j] * bf2f(xr[t][j]);
#pragma unroll
        for (int d = 1; d < 64; d <<= 1) p += __shfl_xor(p, d);
        dot[t] = p * 0.044194173824159216f;  // 1/sqrt(512)
    }
    float mx = fmaxf(fmaxf(dot[0], dot[1]), fmaxf(dot[2], dot[3]));
    float e[4], se = 0.f;
#pragma unroll
    for (int t = 0; t < 4; ++t) { e[t] = expf(dot[t] - mx); se += e[t]; }
    float inv = 1.0f / se;
    float z[8] = {0, 0, 0, 0, 0, 0, 0, 0};
#pragma unroll
    for (int t = 0; t < 4; ++t) {
        float scv = e[t] * inv;
#pragma unroll
        for (int j = 0; j < 8; ++j) z[j] += scv * bf2f(xr[t][j]);
    }
    float s1 = 0.f, s2 = 0.f;
#pragma unroll
    for (int j = 0; j < 8; ++j) { s1 += z[j]; s2 += z[j] * z[j]; }
#pragma unroll
    for (int d = 1; d < 64; d <<= 1) { s1 += __shfl_xor(s1, d); s2 += __shfl_xor(s2, d); }
    float mean = s1 * (1.0f / 512.0f);
    float var  = s2 * (1.0f / 512.0f) - mean * mean;
    float rstd = rsqrtf(var + 1e-5f);
    float4 w0 = *(const float4*)(olnw + lane * 8);
    float4 w1 = *(const float4*)(olnw + lane * 8 + 4);
    float4 b0 = *(const float4*)(olnb + lane * 8);
    float4 b1 = *(const float4*)(olnb + lane * 8 + 4);
    float wv[8] = {w0.x, w0.y, w0.z, w0.w, w1.x, w1.y, w1.z, w1.w};
    float bv[8] = {b0.x, b0.y, b0.z, b0.w, b1.x, b1.y, b1.z, b1.w};
    u16x8 o;
#pragma unroll
    for (int j = 0; j < 8; ++j) o[j] = f2bf((z[j] - mean) * rstd * wv[j] + bv[j]);
    *(u16x8*)(Zb + (size_t)s * 512 + lane * 8) = o;
}

// ---------------- final: y = G(s,256) . w2 + b2 ; wave per sample ----------------
__global__ __launch_bounds__(256) void k_out2(const u16* __restrict__ G, const float* __restrict__ w2,
                                              const float* __restrict__ b2, float* __restrict__ y) {
    int s = blockIdx.x * 4 + (threadIdx.x >> 6);
    int lane = threadIdx.x & 63;
    uint2 u = *(const uint2*)(G + (size_t)s * 256 + lane * 4);
    float4 wv = *(const float4*)(w2 + lane * 4);
    float p = bflo(u.x) * wv.x + bfhi(u.x) * wv.y + bflo(u.y) * wv.z + bfhi(u.y) * wv.w;
#pragma unroll
    for (int d = 1; d < 64; d <<= 1) p += __shfl_xor(p, d);
    if (lane == 0) y[s] = p + b2[0];
}

extern "C" void kernel_launch(void* const* d_in, const int* in_sizes, int n_in,
                              void* d_out, int out_size, void* d_ws, size_t ws_size,
                              hipStream_t stream) {
    const float* x     = (const float*)d_in[0];
    const float* be    = (const float*)d_in[1];
    const float* ln1w  = (const float*)d_in[2];
    const float* ln1b  = (const float*)d_in[3];
    const float* qkvw  = (const float*)d_in[4];
    const float* qkvb  = (const float*)d_in[5];
    const float* projw = (const float*)d_in[6];
    const float* projb = (const float*)d_in[7];
    const float* ln2w  = (const float*)d_in[8];
    const float* ln2b  = (const float*)d_in[9];
    const float* f1w   = (const float*)d_in[10];
    const float* f1b   = (const float*)d_in[11];
    const float* f2w   = (const float*)d_in[12];
    const float* f2b   = (const float*)d_in[13];
    const float* poolq = (const float*)d_in[14];
    const float* poolw = (const float*)d_in[15];
    const float* olnw  = (const float*)d_in[16];
    const float* olnb  = (const float*)d_in[17];
    const float* ow1   = (const float*)d_in[18];
    const float* ob1   = (const float*)d_in[19];
    const float* ow2   = (const float*)d_in[20];
    const float* ob2   = (const float*)d_in[21];
    float* y = (float*)d_out;

    int N = in_sizes[0] / 2048;  // (N,512,4)

    char* p = (char*)d_ws;
    auto take = [&](size_t b) { char* r = p; p += (b + 255) & ~(size_t)255; return r; };
    u16* qkvWb  = (u16*)take((size_t)3145728 * 2);
    u16* projWb = (u16*)take((size_t)1048576 * 2);
    u16* f1Wb   = (u16*)take((size_t)2097152 * 2);
    u16* f2Wb   = (u16*)take((size_t)2097152 * 2);
    u16* ow1b   = (u16*)take((size_t)131072 * 2);
    float* qw   = (float*)take(512 * 4);
    size_t fixedB = (size_t)(p - (char*)d_ws);

    // single chunk; halve only if ws_size forces it.
    int S = N;
    while (S > 256 && fixedB + (size_t)S * 20480 + 65536 > ws_size) S >>= 1;
    int R = S * 4;
    int TM = R / 256;

    u16* Xb    = (u16*)take((size_t)R * 512 * 2);   // persistent bf16 X
    u16* Hb    = (u16*)take((size_t)R * 512 * 2);
    u16* QKVb  = (u16*)take((size_t)R * 1536 * 2);
    u16* Fb  = QKVb;                                   // R x 1024 (FFN phase)
    u16* Gb  = (u16*)((char*)QKVb + (size_t)R * 512 * 2);  // S x 256 (head phase)
    u16* Zb  = Hb;

    // merged weight-convert (5 tensors) + pool-query projection
    k_cvt5<<<8320, 256, 0, stream>>>(qkvw, qkvWb, projw, projWb, f1w, f1Wb,
                                     f2w, f2Wb, ow1, ow1b);
    k_poolq<<<2, 256, 0, stream>>>(poolq, poolw, qw);

    auto gridFor = [](int T) { return T < 256 ? T : 256; };

    for (int c0 = 0; c0 < N; c0 += S) {
        const float* xin = x + (size_t)c0 * 2048;
        k_embed_ln<<<S, 256, 0, stream>>>(xin, be, ln1w, ln1b, Xb, Hb);
        for (int l = 0; l < 4; ++l) {
            { int T = TM * 6;   // QKV: bias, bounce+NT
              k_gemm256<true, false, false, true, true, false><<<gridFor(T), 512, 0, stream>>>(
                  Hb, qkvWb + (size_t)l * 786432, qkvb + l * 1536, QKVb, nullptr,
                  nullptr, nullptr, nullptr, 512, 1536, 6, T); }
            k_attn<<<S, 256, 0, stream>>>(QKVb, Hb);
            { int T = TM * 2;   // proj: resid + fused ln2 -> Hb
              k_gemm256<true, false, true, false, false, true><<<gridFor(T), 512, 0, stream>>>(
                  Hb, projWb + (size_t)l * 262144, projb + l * 512, nullptr, Xb,
                  ln2w + l * 512, ln2b + l * 512, Hb, 512, 512, 2, T); }
            { int T = TM * 4;   // ffn1: bias+gelu, bounce+NT
              k_gemm256<true, true, false, true, true, false><<<gridFor(T), 512, 0, stream>>>(
                  Hb, f1Wb + (size_t)l * 524288, f1b + l * 1024, Fb, nullptr,
                  nullptr, nullptr, nullptr, 512, 1024, 4, T); }
            if (l < 3) {        // ffn2: resid + fused ln1[l+1] -> Hb
                int T = TM * 2;
                k_gemm256<true, false, true, false, false, true><<<gridFor(T), 512, 0, stream>>>(
                    Fb, f2Wb + (size_t)l * 524288, f2b + l * 512, nullptr, Xb,
                    ln1w + (l + 1) * 512, ln1b + (l + 1) * 512, Hb, 1024, 512, 2, T);
            } else {            // last ffn2: plain resid (pool reads raw Xb)
                int T = TM * 2;
                k_gemm256<true, false, true, false, false, false><<<gridFor(T), 512, 0, stream>>>(
                    Fb, f2Wb + (size_t)l * 524288, f2b + l * 512, nullptr, Xb,
                    nullptr, nullptr, nullptr, 1024, 512, 2, T);
            }
        }
        k_pool<<<S / 4, 256, 0, stream>>>(Xb, qw, olnw, olnb, Zb);
        { int T = S / 256;
          k_gemm256<true, true, false, false, false, false><<<gridFor(T), 512, 0, stream>>>(
              Zb, ow1b, ob1, Gb, nullptr, nullptr, nullptr, nullptr, 512, 256, 1, T); }
        k_out2<<<S / 4, 256, 0, stream>>>(Gb, ow2, ob2, y + c0);
    }
    (void)n_in; (void)out_size; (void)ws_size;
}

// Round 7
// 4330.857 us; speedup vs baseline: 1.0796x; 1.0796x over previous
//
#include <hip/hip_runtime.h>

typedef unsigned short u16;
typedef unsigned int u32;
typedef __attribute__((ext_vector_type(8))) short s16x8;
typedef __attribute__((ext_vector_type(8))) unsigned short u16x8;
typedef __attribute__((ext_vector_type(4))) float f32x4;
typedef __attribute__((ext_vector_type(4))) unsigned int u32x4;

__device__ __forceinline__ u16 f2bf(float f) {
    u32 u = __float_as_uint(f);
    u32 r = (u + 0x7fffu + ((u >> 16) & 1u)) >> 16;
    return (u16)r;
}
__device__ __forceinline__ float bf2f(u16 u) { return __uint_as_float(((u32)u) << 16); }
__device__ __forceinline__ float bflo(u32 u) { return __uint_as_float(u << 16); }
__device__ __forceinline__ float bfhi(u32 u) { return __uint_as_float(u & 0xffff0000u); }
__device__ __forceinline__ float gelu_exact(float v) {
    return 0.5f * v * (1.0f + erff(v * 0.70710678118654752f));
}

// async global -> LDS, 16B per lane. LDS dest = wave-uniform base + lane*16.
__device__ __forceinline__ void gload16(const void* g, void* l) {
    __builtin_amdgcn_global_load_lds(
        (const __attribute__((address_space(1))) u32*)g,
        (__attribute__((address_space(3))) u32*)l, 16, 0, 0);
}

// ---------------- fp32 -> bf16 convert: 5 weight tensors in one launch ----------------
__global__ __launch_bounds__(256) void k_cvt5(const float* __restrict__ s0, u16* __restrict__ d0,
                                              const float* __restrict__ s1, u16* __restrict__ d1,
                                              const float* __restrict__ s2, u16* __restrict__ d2,
                                              const float* __restrict__ s3, u16* __restrict__ d3,
                                              const float* __restrict__ s4, u16* __restrict__ d4) {
    int i = blockIdx.x * 256 + threadIdx.x;
    const float* s; u16* d; int off;
    if (i < 786432)       { s = s0; d = d0; off = i; }
    else if (i < 1048576) { s = s1; d = d1; off = i - 786432; }
    else if (i < 1572864) { s = s2; d = d2; off = i - 1048576; }
    else if (i < 2097152) { s = s3; d = d3; off = i - 1572864; }
    else                  { s = s4; d = d4; off = i - 2097152; }
    float4 v = *(const float4*)(s + (size_t)off * 4);
    u16 o0 = f2bf(v.x), o1 = f2bf(v.y), o2 = f2bf(v.z), o3 = f2bf(v.w);
    uint2 o; o.x = (u32)o0 | ((u32)o1 << 16); o.y = (u32)o2 | ((u32)o3 << 16);
    *(uint2*)(d + (size_t)off * 4) = o;
}

// ---------------- qw = pool_w^T . pool_q  (512 outputs, f32) ----------------
__global__ __launch_bounds__(256) void k_poolq(const float* __restrict__ pq,
                                               const float* __restrict__ W,
                                               float* __restrict__ qw) {
    int d = blockIdx.x * 256 + threadIdx.x;
    float s = 0.f;
    for (int e = 0; e < 512; ++e) s += pq[e] * W[(size_t)e * 512 + d];
    qw[d] = s;
}

// ---------------- embed + ln1(l=0) fused: one block per sample ----------------
__global__ __launch_bounds__(256) void k_embed_ln(const float* __restrict__ x,
                                                  const float* __restrict__ be,
                                                  const float* __restrict__ w,
                                                  const float* __restrict__ b,
                                                  u16* __restrict__ Xb,
                                                  u16* __restrict__ Hb) {
    __shared__ u16 ld[4][512];
    int s = blockIdx.x;
    int tid = threadIdx.x;
    const float* xs = x + (size_t)s * 2048;
#pragma unroll
    for (int i = 0; i < 2; ++i) {
        int d = tid + i * 256;
        float4 v = *(const float4*)(xs + d * 4);
        ld[0][d] = f2bf(v.x + be[d]);
        ld[1][d] = f2bf(v.y + be[512 + d]);
        ld[2][d] = f2bf(v.z + be[1024 + d]);
        ld[3][d] = f2bf(v.w + be[1536 + d]);
    }
    __syncthreads();
    int t = tid >> 6, lane = tid & 63;
    u16x8 raw = *(const u16x8*)(&ld[t][lane * 8]);
    *(u16x8*)(Xb + ((size_t)s * 4 + t) * 512 + lane * 8) = raw;
    float a[8];
#pragma unroll
    for (int j = 0; j < 8; ++j) a[j] = bf2f(raw[j]);
    float s1 = 0.f, s2 = 0.f;
#pragma unroll
    for (int j = 0; j < 8; ++j) { s1 += a[j]; s2 += a[j] * a[j]; }
#pragma unroll
    for (int d = 1; d < 64; d <<= 1) { s1 += __shfl_xor(s1, d); s2 += __shfl_xor(s2, d); }
    float mean = s1 * (1.0f / 512.0f);
    float var  = s2 * (1.0f / 512.0f) - mean * mean;
    float rstd = rsqrtf(var + 1e-5f);
    float4 w0 = *(const float4*)(w + lane * 8);
    float4 w1 = *(const float4*)(w + lane * 8 + 4);
    float4 b0 = *(const float4*)(b + lane * 8);
    float4 b1 = *(const float4*)(b + lane * 8 + 4);
    float wv[8] = {w0.x, w0.y, w0.z, w0.w, w1.x, w1.y, w1.z, w1.w};
    float bv[8] = {b0.x, b0.y, b0.z, b0.w, b1.x, b1.y, b1.z, b1.w};
    u16x8 o;
#pragma unroll
    for (int j = 0; j < 8; ++j) o[j] = f2bf((a[j] - mean) * rstd * wv[j] + bv[j]);
    *(u16x8*)(Hb + ((size_t)s * 4 + t) * 512 + lane * 8) = o;
}

// ---------------- layernorm: bf16 row (512) -> bf16 row; wave per row ----------------
__global__ __launch_bounds__(256) void k_ln(const u16* __restrict__ Xb,
                                            const float* __restrict__ w,
                                            const float* __restrict__ b,
                                            u16* __restrict__ H) {
    int row = blockIdx.x * 4 + (threadIdx.x >> 6);
    int lane = threadIdx.x & 63;
    u16x8 xv = *(const u16x8*)(Xb + (size_t)row * 512 + lane * 8);
    float a[8];
#pragma unroll
    for (int j = 0; j < 8; ++j) a[j] = bf2f(xv[j]);
    float s1 = 0.f, s2 = 0.f;
#pragma unroll
    for (int j = 0; j < 8; ++j) { s1 += a[j]; s2 += a[j] * a[j]; }
#pragma unroll
    for (int d = 1; d < 64; d <<= 1) { s1 += __shfl_xor(s1, d); s2 += __shfl_xor(s2, d); }
    float mean = s1 * (1.0f / 512.0f);
    float var  = s2 * (1.0f / 512.0f) - mean * mean;
    float rstd = rsqrtf(var + 1e-5f);
    float4 w0 = *(const float4*)(w + lane * 8);
    float4 w1 = *(const float4*)(w + lane * 8 + 4);
    float4 b0 = *(const float4*)(b + lane * 8);
    float4 b1 = *(const float4*)(b + lane * 8 + 4);
    float wv[8] = {w0.x, w0.y, w0.z, w0.w, w1.x, w1.y, w1.z, w1.w};
    float bv[8] = {b0.x, b0.y, b0.z, b0.w, b1.x, b1.y, b1.z, b1.w};
    u16x8 o;
#pragma unroll
    for (int j = 0; j < 8; ++j) o[j] = f2bf((a[j] - mean) * rstd * wv[j] + bv[j]);
    *(u16x8*)(H + (size_t)row * 512 + lane * 8) = o;
}

// ---------------- GEMM: persistent 8-phase (cross-tile pipelined) ----------------
// 256x256 tile, BK=64, 8 waves, 2x64KB LDS bufs, persistent blocks.
// XCD-aware interleaved panel-sharing schedule (verified R2: FETCH ~ideal).
// RESID: bf16 RMW of Xb. BOUNCE+NT (QKV/FFN1; QKV verified R1/R5): per-wave
// 2KB LDS bounce -> full-128B-line NT stores for streaming outputs > L3.
template <bool BIAS, bool GELU_, bool RESID, bool BOUNCE, bool NT>
__global__ __launch_bounds__(512, 2) void k_gemm256(const u16* __restrict__ A,
                                                    const u16* __restrict__ W,
                                                    const float* __restrict__ bias,
                                                    u16* __restrict__ Cb,
                                                    u16* __restrict__ Xbres,
                                                    int K, int ncols, int TN, int T) {
    __shared__ __align__(16) u16 lds[2 * 32768];
    __shared__ __align__(16) u16 bounce[8192];  // 16 KB: 2 KB per wave
    int tid = threadIdx.x;
    int lane = tid & 63;
    int wid = tid >> 6;
    int G = gridDim.x, b = blockIdx.x;
    int start, end, step;
    if ((G & 7) == 0) {
        int xcd = b & 7, nxb = G >> 3, j = b >> 3;
        start = (int)(((long long)xcd * T) >> 3) + j;
        end   = (int)(((long long)(xcd + 1) * T) >> 3);
        step  = nxb;
    } else {
        start = (int)(((long long)b * T) / G);
        end   = (int)(((long long)(b + 1) * T) / G);
        step  = 1;
    }
    if (start >= end) return;
    int NS = K >> 6;   // K-steps of 64, even (K in {512,1024})
    int mgrp = wid >> 2, ngrp = wid & 3;

    f32x4 acc[8][4];
#pragma unroll
    for (int i = 0; i < 8; ++i)
#pragma unroll
        for (int j = 0; j < 4; ++j) acc[i][j] = (f32x4){0.f, 0.f, 0.f, 0.f};

    int srow = tid >> 3;
    int sel  = (((tid & 7) * 16) ^ ((srow & 7) << 4)) >> 1;
    size_t K64 = (size_t)K * 64;
    char* ldsB = (char*)lds;
    int wdst = wid * 1024;

    const u16 *cA0, *cA1, *cB0, *cB1, *nA0, *nA1, *nB0, *nB1;
    int cm0, cn0, nm0, nn0;
    auto tilePtrs = [&](int ti, const u16*& a0, const u16*& a1,
                        const u16*& b0, const u16*& b1, int& m0o, int& n0o) {
        int bx = ti / TN, by = ti - bx * TN;
        int m0 = bx * 256, n0 = by * 256;
        a0 = A + (size_t)(m0 + srow) * K + sel;
        a1 = A + (size_t)(m0 + 128 + srow) * K + sel;
        b0 = W + (size_t)(n0 + srow) * K + sel;
        b1 = W + (size_t)(n0 + 128 + srow) * K + sel;
        m0o = m0; n0o = n0;
    };

    auto S_Aq12 = [&](const u16* a0, const u16* a1, int s) {
        char* d = ldsB + (s & 1) * 65536 + wdst;
        gload16(a0 + (size_t)s * 64, d);
        gload16(a1 + (size_t)s * 64, d + 16384);
    };
    auto S_Aq34 = [&](const u16* a0, const u16* a1, int s) {
        char* d = ldsB + (s & 1) * 65536 + 8192 + wdst;
        gload16(a0 + K64 + (size_t)s * 64, d);
        gload16(a1 + K64 + (size_t)s * 64, d + 16384);
    };
    auto S_Blo = [&](const u16* b0, int s) {
        char* d = ldsB + (s & 1) * 65536 + 32768 + wdst;
        gload16(b0 + (size_t)s * 64, d);
        gload16(b0 + K64 + (size_t)s * 64, d + 8192);
    };
    auto S_Bhi = [&](const u16* b1, int s) {
        char* d = ldsB + (s & 1) * 65536 + 49152 + wdst;
        gload16(b1 + (size_t)s * 64, d);
        gload16(b1 + K64 + (size_t)s * 64, d + 8192);
    };

    int arow = mgrp * 128 + (lane & 15);
    int brow = ngrp * 64 + (lane & 15);
    int sub = (lane >> 4) << 4;
    int amask = ((arow & 7) << 4), bmask = ((brow & 7) << 4);
    int aoff0 = arow * 128 + (sub ^ amask);
    int boff0 = 32768 + brow * 128 + (sub ^ bmask);
    int aoff1 = arow * 128 + ((sub | 64) ^ amask);
    int boff1 = 32768 + brow * 128 + ((sub | 64) ^ bmask);

    tilePtrs(start, cA0, cA1, cB0, cB1, cm0, cn0);
    S_Blo(cB0, 0); S_Bhi(cB1, 0); S_Aq12(cA0, cA1, 0); S_Aq34(cA0, cA1, 0);
    S_Blo(cB0, 1); S_Bhi(cB1, 1); S_Aq12(cA0, cA1, 1);
    asm volatile("s_waitcnt vmcnt(6)" ::: "memory");
    __builtin_amdgcn_s_barrier();

    for (int ti = start; ti < end; ti += step) {
        bool hasNext = (ti + step < end);
        if (hasNext) tilePtrs(ti + step, nA0, nA1, nB0, nB1, nm0, nn0);

        s16x8 bfr[4][2];
        for (int s = 0; s < NS; ++s) {
            const char* sb = ldsB + (s & 1) * 65536;
            int st = s + 1, st2 = s + 2;
            bool n1 = st < NS, n2 = st2 < NS;
            // ---------- phase 1 ----------
            s16x8 af[2][2];
#pragma unroll
            for (int ni = 0; ni < 4; ++ni) {
                bfr[ni][0] = *(const s16x8*)(sb + boff0 + ni * 2048);
                bfr[ni][1] = *(const s16x8*)(sb + boff1 + ni * 2048);
            }
            af[0][0] = *(const s16x8*)(sb + aoff0);
            af[0][1] = *(const s16x8*)(sb + aoff1);
            af[1][0] = *(const s16x8*)(sb + aoff0 + 2048);
            af[1][1] = *(const s16x8*)(sb + aoff1 + 2048);
            if (n1) S_Aq34(cA0, cA1, st); else if (hasNext) S_Aq34(nA0, nA1, st - NS);
            __builtin_amdgcn_s_barrier();
            __builtin_amdgcn_s_setprio(1);
#pragma unroll
            for (int mj = 0; mj < 2; ++mj)
#pragma unroll
                for (int ni = 0; ni < 4; ++ni) {
                    acc[mj][ni] = __builtin_amdgcn_mfma_f32_16x16x32_bf16(bfr[ni][0], af[mj][0], acc[mj][ni], 0, 0, 0);
                    acc[mj][ni] = __builtin_amdgcn_mfma_f32_16x16x32_bf16(bfr[ni][1], af[mj][1], acc[mj][ni], 0, 0, 0);
                }
            __builtin_amdgcn_s_setprio(0);
            __builtin_amdgcn_s_barrier();
            // ---------- phase 2 ----------
#pragma unroll
            for (int mj = 0; mj < 2; ++mj) {
                af[mj][0] = *(const s16x8*)(sb + aoff0 + (2 + mj) * 2048);
                af[mj][1] = *(const s16x8*)(sb + aoff1 + (2 + mj) * 2048);
            }
            if (n2) S_Blo(cB0, st2); else if (hasNext) S_Blo(nB0, st2 - NS);
            __builtin_amdgcn_s_barrier();
            __builtin_amdgcn_s_setprio(1);
#pragma unroll
            for (int mj = 0; mj < 2; ++mj)
#pragma unroll
                for (int ni = 0; ni < 4; ++ni) {
                    acc[2 + mj][ni] = __builtin_amdgcn_mfma_f32_16x16x32_bf16(bfr[ni][0], af[mj][0], acc[2 + mj][ni], 0, 0, 0);
                    acc[2 + mj][ni] = __builtin_amdgcn_mfma_f32_16x16x32_bf16(bfr[ni][1], af[mj][1], acc[2 + mj][ni], 0, 0, 0);
                }
            __builtin_amdgcn_s_setprio(0);
            __builtin_amdgcn_s_barrier();
            // ---------- phase 3 ----------
#pragma unroll
            for (int mj = 0; mj < 2; ++mj) {
                af[mj][0] = *(const s16x8*)(sb + aoff0 + (4 + mj) * 2048);
                af[mj][1] = *(const s16x8*)(sb + aoff1 + (4 + mj) * 2048);
            }
            if (n2) S_Bhi(cB1, st2); else if (hasNext) S_Bhi(nB1, st2 - NS);
            __builtin_amdgcn_s_barrier();
            __builtin_amdgcn_s_setprio(1);
#pragma unroll
            for (int mj = 0; mj < 2; ++mj)
#pragma unroll
                for (int ni = 0; ni < 4; ++ni) {
                    acc[4 + mj][ni] = __builtin_amdgcn_mfma_f32_16x16x32_bf16(bfr[ni][0], af[mj][0], acc[4 + mj][ni], 0, 0, 0);
                    acc[4 + mj][ni] = __builtin_amdgcn_mfma_f32_16x16x32_bf16(bfr[ni][1], af[mj][1], acc[4 + mj][ni], 0, 0, 0);
                }
            __builtin_amdgcn_s_setprio(0);
            __builtin_amdgcn_s_barrier();
            // ---------- phase 4 ----------
#pragma unroll
            for (int mj = 0; mj < 2; ++mj) {
                af[mj][0] = *(const s16x8*)(sb + aoff0 + (6 + mj) * 2048);
                af[mj][1] = *(const s16x8*)(sb + aoff1 + (6 + mj) * 2048);
            }
            if (n2) S_Aq12(cA0, cA1, st2); else if (hasNext) S_Aq12(nA0, nA1, st2 - NS);
            __builtin_amdgcn_s_barrier();
            __builtin_amdgcn_s_setprio(1);
#pragma unroll
            for (int mj = 0; mj < 2; ++mj)
#pragma unroll
                for (int ni = 0; ni < 4; ++ni) {
                    acc[6 + mj][ni] = __builtin_amdgcn_mfma_f32_16x16x32_bf16(bfr[ni][0], af[mj][0], acc[6 + mj][ni], 0, 0, 0);
                    acc[6 + mj][ni] = __builtin_amdgcn_mfma_f32_16x16x32_bf16(bfr[ni][1], af[mj][1], acc[6 + mj][ni], 0, 0, 0);
                }
            __builtin_amdgcn_s_setprio(0);
            bool staged24 = n2 || hasNext;
            bool last = (s == NS - 1) && !hasNext;
            if (!last) {
                if (staged24) asm volatile("s_waitcnt vmcnt(6)" ::: "memory");
                else          asm volatile("s_waitcnt vmcnt(0)" ::: "memory");
                __builtin_amdgcn_s_barrier();
            }
        }

        // ---- epilogue for tile ti ----
        int r_lane = lane & 15, cg = lane >> 4;
        float4 bb[4];
        if (BIAS) {
#pragma unroll
            for (int ni = 0; ni < 4; ++ni)
                bb[ni] = *(const float4*)(bias + cn0 + ngrp * 64 + ni * 16 + cg * 4);
        }
        if (BOUNCE) {
            u16* bw = bounce + wid * 1024;
            int qrow = lane >> 3, kc = lane & 7;
#pragma unroll
            for (int mi = 0; mi < 8; ++mi) {
                int rowbase = cm0 + mgrp * 128 + mi * 16;
#pragma unroll
                for (int ni = 0; ni < 4; ++ni) {
                    f32x4 v = acc[mi][ni];
                    if (BIAS) { v[0] += bb[ni].x; v[1] += bb[ni].y; v[2] += bb[ni].z; v[3] += bb[ni].w; }
                    if (GELU_) {
#pragma unroll
                        for (int j = 0; j < 4; ++j) v[j] = gelu_exact(v[j]);
                    }
                    uint2 o;
                    o.x = (u32)f2bf(v[0]) | ((u32)f2bf(v[1]) << 16);
                    o.y = (u32)f2bf(v[2]) | ((u32)f2bf(v[3]) << 16);
                    int slot = (4 * ni + cg) ^ (r_lane & 14);
                    *(uint2*)(bw + r_lane * 64 + slot * 4) = o;
                    acc[mi][ni] = (f32x4){0.f, 0.f, 0.f, 0.f};
                }
                asm volatile("s_waitcnt lgkmcnt(0)" ::: "memory");
#pragma unroll
                for (int h = 0; h < 2; ++h) {
                    int rd = h * 8 + qrow;
                    int e = (2 * kc) ^ (rd & 14);
                    u32x4 t = *(const u32x4*)(bw + rd * 64 + e * 4);
                    int row = rowbase + rd;
                    int c2 = cn0 + ngrp * 64 + kc * 8;
                    u16* dst = Cb + (size_t)row * ncols + c2;
                    if (NT) __builtin_nontemporal_store(t, (u32x4*)dst);
                    else    *(u32x4*)dst = t;
                }
                asm volatile("s_waitcnt lgkmcnt(0)" ::: "memory");
            }
        } else {
#pragma unroll
            for (int mi = 0; mi < 8; ++mi) {
                int row = cm0 + mgrp * 128 + mi * 16 + r_lane;
#pragma unroll
                for (int ni = 0; ni < 4; ++ni) {
                    int c = cn0 + ngrp * 64 + ni * 16 + cg * 4;
                    f32x4 v = acc[mi][ni];
                    if (BIAS) { v[0] += bb[ni].x; v[1] += bb[ni].y; v[2] += bb[ni].z; v[3] += bb[ni].w; }
                    if (GELU_) {
#pragma unroll
                        for (int j = 0; j < 4; ++j) v[j] = gelu_exact(v[j]);
                    }
                    if (RESID) {
                        u16* px = Xbres + (size_t)row * 512 + c;
                        uint2 xv = *(uint2*)px;
                        float x0 = bflo(xv.x) + v[0];
                        float x1 = bfhi(xv.x) + v[1];
                        float x2 = bflo(xv.y) + v[2];
                        float x3 = bfhi(xv.y) + v[3];
                        uint2 o;
                        o.x = (u32)f2bf(x0) | ((u32)f2bf(x1) << 16);
                        o.y = (u32)f2bf(x2) | ((u32)f2bf(x3) << 16);
                        *(uint2*)px = o;
                    } else {
                        u32 lo = (u32)f2bf(v[0]) | ((u32)f2bf(v[1]) << 16);
                        u32 hi = (u32)f2bf(v[2]) | ((u32)f2bf(v[3]) << 16);
                        uint2 o; o.x = lo; o.y = hi;
                        *(uint2*)(Cb + (size_t)row * ncols + c) = o;
                    }
                    acc[mi][ni] = (f32x4){0.f, 0.f, 0.f, 0.f};
                }
            }
        }
        cA0 = nA0; cA1 = nA1; cB0 = nB0; cB1 = nB1; cm0 = nm0; cn0 = nn0;
    }
}

// ---------------- attention: T=4, per (sample, head) per wave ----------------
__global__ __launch_bounds__(256) void k_attn(const u16* __restrict__ QKV, u16* __restrict__ O) {
    int task = blockIdx.x * 4 + (threadIdx.x >> 6);
    int lane = threadIdx.x & 63;
    int s = task >> 2, h = task & 3;
    const u16* base = QKV + (size_t)s * 4 * 1536 + h * 128;
    float q[4][2], k[4][2], v[4][2];
#pragma unroll
    for (int t = 0; t < 4; ++t) {
        const u16* row = base + t * 1536;
        u32 uq = *(const u32*)(row + lane * 2);
        u32 uk = *(const u32*)(row + 512 + lane * 2);
        u32 uv = *(const u32*)(row + 1024 + lane * 2);
        q[t][0] = bflo(uq); q[t][1] = bfhi(uq);
        k[t][0] = bflo(uk); k[t][1] = bfhi(uk);
        v[t][0] = bflo(uv); v[t][1] = bfhi(uv);
    }
    float sc[4][4];
#pragma unroll
    for (int i = 0; i < 4; ++i)
#pragma unroll
        for (int j = 0; j < 4; ++j) {
            float p = q[i][0] * k[j][0] + q[i][1] * k[j][1];
#pragma unroll
            for (int d = 1; d < 64; d <<= 1) p += __shfl_xor(p, d);
            sc[i][j] = p * 0.08838834764831845f;  // 1/sqrt(128)
        }
    float o[4][2];
#pragma unroll
    for (int i = 0; i < 4; ++i) {
        float mx = fmaxf(fmaxf(sc[i][0], sc[i][1]), fmaxf(sc[i][2], sc[i][3]));
        float e0 = expf(sc[i][0] - mx), e1 = expf(sc[i][1] - mx);
        float e2 = expf(sc[i][2] - mx), e3 = expf(sc[i][3] - mx);
        float inv = 1.0f / (e0 + e1 + e2 + e3);
        float a0 = e0 * inv, a1 = e1 * inv, a2 = e2 * inv, a3 = e3 * inv;
        o[i][0] = a0 * v[0][0] + a1 * v[1][0] + a2 * v[2][0] + a3 * v[3][0];
        o[i][1] = a0 * v[0][1] + a1 * v[1][1] + a2 * v[2][1] + a3 * v[3][1];
    }
#pragma unroll
    for (int i = 0; i < 4; ++i) {
        u32 pk = (u32)f2bf(o[i][0]) | ((u32)f2bf(o[i][1]) << 16);
        *(u32*)(O + ((size_t)s * 4 + i) * 512 + h * 128 + lane * 2) = pk;
    }
}

// ---------------- pooling: score via qw, z, out-LN -> Zb bf16 ; wave per sample ----------------
__global__ __launch_bounds__(256) void k_pool(const u16* __restrict__ Xb, const float* __restrict__ qw,
                                              const float* __restrict__ olnw, const float* __restrict__ olnb,
                                              u16* __restrict__ Zb) {
    int s = blockIdx.x * 4 + (threadIdx.x >> 6);
    int lane = threadIdx.x & 63;
    float4 q0 = *(const float4*)(qw + lane * 8);
    float4 q1 = *(const float4*)(qw + lane * 8 + 4);
    float qv[8] = {q0.x, q0.y, q0.z, q0.w, q1.x, q1.y, q1.z, q1.w};
    u16x8 xr[4];
    float dot[4];
#pragma unroll
    for (int t = 0; t < 4; ++t) {
        xr[t] = *(const u16x8*)(Xb + ((size_t)s * 4 + t) * 512 + lane * 8);
        float p = 0.f;
#pragma unroll
        for (int j = 0; j < 8; ++j) p += qv[j] * bf2f(xr[t][j]);
#pragma unroll
        for (int d = 1; d < 64; d <<= 1) p += __shfl_xor(p, d);
        dot[t] = p * 0.044194173824159216f;  // 1/sqrt(512)
    }
    float mx = fmaxf(fmaxf(dot[0], dot[1]), fmaxf(dot[2], dot[3]));
    float e[4], se = 0.f;
#pragma unroll
    for (int t = 0; t < 4; ++t) { e[t] = expf(dot[t] - mx); se += e[t]; }
    float inv = 1.0f / se;
    float z[8] = {0, 0, 0, 0, 0, 0, 0, 0};
#pragma unroll
    for (int t = 0; t < 4; ++t) {
        float scv = e[t] * inv;
#pragma unroll
        for (int j = 0; j < 8; ++j) z[j] += scv * bf2f(xr[t][j]);
    }
    float s1 = 0.f, s2 = 0.f;
#pragma unroll
    for (int j = 0; j < 8; ++j) { s1 += z[j]; s2 += z[j] * z[j]; }
#pragma unroll
    for (int d = 1; d < 64; d <<= 1) { s1 += __shfl_xor(s1, d); s2 += __shfl_xor(s2, d); }
    float mean = s1 * (1.0f / 512.0f);
    float var  = s2 * (1.0f / 512.0f) - mean * mean;
    float rstd = rsqrtf(var + 1e-5f);
    float4 w0 = *(const float4*)(olnw + lane * 8);
    float4 w1 = *(const float4*)(olnw + lane * 8 + 4);
    float4 b0 = *(const float4*)(olnb + lane * 8);
    float4 b1 = *(const float4*)(olnb + lane * 8 + 4);
    float wv[8] = {w0.x, w0.y, w0.z, w0.w, w1.x, w1.y, w1.z, w1.w};
    float bv[8] = {b0.x, b0.y, b0.z, b0.w, b1.x, b1.y, b1.z, b1.w};
    u16x8 o;
#pragma unroll
    for (int j = 0; j < 8; ++j) o[j] = f2bf((z[j] - mean) * rstd * wv[j] + bv[j]);
    *(u16x8*)(Zb + (size_t)s * 512 + lane * 8) = o;
}

// ---------------- final: y = G(s,256) . w2 + b2 ; wave per sample ----------------
__global__ __launch_bounds__(256) void k_out2(const u16* __restrict__ G, const float* __restrict__ w2,
                                              const float* __restrict__ b2, float* __restrict__ y) {
    int s = blockIdx.x * 4 + (threadIdx.x >> 6);
    int lane = threadIdx.x & 63;
    uint2 u = *(const uint2*)(G + (size_t)s * 256 + lane * 4);
    float4 wv = *(const float4*)(w2 + lane * 4);
    float p = bflo(u.x) * wv.x + bfhi(u.x) * wv.y + bflo(u.y) * wv.z + bfhi(u.y) * wv.w;
#pragma unroll
    for (int d = 1; d < 64; d <<= 1) p += __shfl_xor(p, d);
    if (lane == 0) y[s] = p + b2[0];
}

extern "C" void kernel_launch(void* const* d_in, const int* in_sizes, int n_in,
                              void* d_out, int out_size, void* d_ws, size_t ws_size,
                              hipStream_t stream) {
    const float* x     = (const float*)d_in[0];
    const float* be    = (const float*)d_in[1];
    const float* ln1w  = (const float*)d_in[2];
    const float* ln1b  = (const float*)d_in[3];
    const float* qkvw  = (const float*)d_in[4];
    const float* qkvb  = (const float*)d_in[5];
    const float* projw = (const float*)d_in[6];
    const float* projb = (const float*)d_in[7];
    const float* ln2w  = (const float*)d_in[8];
    const float* ln2b  = (const float*)d_in[9];
    const float* f1w   = (const float*)d_in[10];
    const float* f1b   = (const float*)d_in[11];
    const float* f2w   = (const float*)d_in[12];
    const float* f2b   = (const float*)d_in[13];
    const float* poolq = (const float*)d_in[14];
    const float* poolw = (const float*)d_in[15];
    const float* olnw  = (const float*)d_in[16];
    const float* olnb  = (const float*)d_in[17];
    const float* ow1   = (const float*)d_in[18];
    const float* ob1   = (const float*)d_in[19];
    const float* ow2   = (const float*)d_in[20];
    const float* ob2   = (const float*)d_in[21];
    float* y = (float*)d_out;

    int N = in_sizes[0] / 2048;  // (N,512,4)

    char* p = (char*)d_ws;
    auto take = [&](size_t b) { char* r = p; p += (b + 255) & ~(size_t)255; return r; };
    u16* qkvWb  = (u16*)take((size_t)3145728 * 2);
    u16* projWb = (u16*)take((size_t)1048576 * 2);
    u16* f1Wb   = (u16*)take((size_t)2097152 * 2);
    u16* f2Wb   = (u16*)take((size_t)2097152 * 2);
    u16* ow1b   = (u16*)take((size_t)131072 * 2);
    float* qw   = (float*)take(512 * 4);
    size_t fixedB = (size_t)(p - (char*)d_ws);

    // single chunk; halve only if ws_size forces it.
    int S = N;
    while (S > 256 && fixedB + (size_t)S * 20480 + 65536 > ws_size) S >>= 1;
    int R = S * 4;
    int TM = R / 256;

    u16* Xb    = (u16*)take((size_t)R * 512 * 2);   // persistent bf16 X
    u16* Hb    = (u16*)take((size_t)R * 512 * 2);
    u16* QKVb  = (u16*)take((size_t)R * 1536 * 2);
    u16* Fb  = QKVb;                                   // R x 1024 (FFN phase)
    u16* Gb  = (u16*)((char*)QKVb + (size_t)R * 512 * 2);  // S x 256 (head phase)
    u16* Zb  = Hb;

    // merged weight-convert (5 tensors) + pool-query projection
    k_cvt5<<<8320, 256, 0, stream>>>(qkvw, qkvWb, projw, projWb, f1w, f1Wb,
                                     f2w, f2Wb, ow1, ow1b);
    k_poolq<<<2, 256, 0, stream>>>(poolq, poolw, qw);

    auto gridFor = [](int T) { return T < 256 ? T : 256; };

    for (int c0 = 0; c0 < N; c0 += S) {
        const float* xin = x + (size_t)c0 * 2048;
        k_embed_ln<<<S, 256, 0, stream>>>(xin, be, ln1w, ln1b, Xb, Hb);
        for (int l = 0; l < 4; ++l) {
            if (l > 0)
                k_ln<<<R / 4, 256, 0, stream>>>(Xb, ln1w + l * 512, ln1b + l * 512, Hb);
            { int T = TM * 6;   // QKV: bias, bounce+NT (verified R1/R5)
              k_gemm256<true, false, false, true, true><<<gridFor(T), 512, 0, stream>>>(
                  Hb, qkvWb + (size_t)l * 786432, qkvb + l * 1536, QKVb, nullptr, 512, 1536, 6, T); }
            k_attn<<<S, 256, 0, stream>>>(QKVb, Hb);
            { int T = TM * 2;   // proj: resid RMW
              k_gemm256<true, false, true, false, false><<<gridFor(T), 512, 0, stream>>>(
                  Hb, projWb + (size_t)l * 262144, projb + l * 512, nullptr, Xb, 512, 512, 2, T); }
            k_ln<<<R / 4, 256, 0, stream>>>(Xb, ln2w + l * 512, ln2b + l * 512, Hb);
            { int T = TM * 4;   // ffn1: bias+gelu, bounce+NT
              k_gemm256<true, true, false, true, true><<<gridFor(T), 512, 0, stream>>>(
                  Hb, f1Wb + (size_t)l * 524288, f1b + l * 1024, Fb, nullptr, 512, 1024, 4, T); }
            { int T = TM * 2;   // ffn2: resid RMW
              k_gemm256<true, false, true, false, false><<<gridFor(T), 512, 0, stream>>>(
                  Fb, f2Wb + (size_t)l * 524288, f2b + l * 512, nullptr, Xb, 1024, 512, 2, T); }
        }
        k_pool<<<S / 4, 256, 0, stream>>>(Xb, qw, olnw, olnb, Zb);
        { int T = S / 256;
          k_gemm256<true, true, false, false, false><<<gridFor(T), 512, 0, stream>>>(
              Zb, ow1b, ob1, Gb, nullptr, 512, 256, 1, T); }
        k_out2<<<S / 4, 256, 0, stream>>>(Gb, ow2, ob2, y + c0);
    }
    (void)n_in; (void)out_size; (void)ws_size;
}

// Round 8
// 4288.954 us; speedup vs baseline: 1.0902x; 1.0098x over previous
//
#include <hip/hip_runtime.h>

typedef unsigned short u16;
typedef unsigned int u32;
typedef __attribute__((ext_vector_type(8))) short s16x8;
typedef __attribute__((ext_vector_type(8))) unsigned short u16x8;
typedef __attribute__((ext_vector_type(4))) float f32x4;
typedef __attribute__((ext_vector_type(4))) unsigned int u32x4;

__device__ __forceinline__ u16 f2bf(float f) {
    u32 u = __float_as_uint(f);
    u32 r = (u + 0x7fffu + ((u >> 16) & 1u)) >> 16;
    return (u16)r;
}
__device__ __forceinline__ float bf2f(u16 u) { return __uint_as_float(((u32)u) << 16); }
__device__ __forceinline__ float bflo(u32 u) { return __uint_as_float(u << 16); }
__device__ __forceinline__ float bfhi(u32 u) { return __uint_as_float(u & 0xffff0000u); }
__device__ __forceinline__ float gelu_exact(float v) {
    return 0.5f * v * (1.0f + erff(v * 0.70710678118654752f));
}

// async global -> LDS, 16B per lane. LDS dest = wave-uniform base + lane*16.
__device__ __forceinline__ void gload16(const void* g, void* l) {
    __builtin_amdgcn_global_load_lds(
        (const __attribute__((address_space(1))) u32*)g,
        (__attribute__((address_space(3))) u32*)l, 16, 0, 0);
}

// ---------------- fp32 -> bf16 convert: 5 weight tensors in one launch ----------------
__global__ __launch_bounds__(256) void k_cvt5(const float* __restrict__ s0, u16* __restrict__ d0,
                                              const float* __restrict__ s1, u16* __restrict__ d1,
                                              const float* __restrict__ s2, u16* __restrict__ d2,
                                              const float* __restrict__ s3, u16* __restrict__ d3,
                                              const float* __restrict__ s4, u16* __restrict__ d4) {
    int i = blockIdx.x * 256 + threadIdx.x;
    const float* s; u16* d; int off;
    if (i < 786432)       { s = s0; d = d0; off = i; }
    else if (i < 1048576) { s = s1; d = d1; off = i - 786432; }
    else if (i < 1572864) { s = s2; d = d2; off = i - 1048576; }
    else if (i < 2097152) { s = s3; d = d3; off = i - 1572864; }
    else                  { s = s4; d = d4; off = i - 2097152; }
    float4 v = *(const float4*)(s + (size_t)off * 4);
    u16 o0 = f2bf(v.x), o1 = f2bf(v.y), o2 = f2bf(v.z), o3 = f2bf(v.w);
    uint2 o; o.x = (u32)o0 | ((u32)o1 << 16); o.y = (u32)o2 | ((u32)o3 << 16);
    *(uint2*)(d + (size_t)off * 4) = o;
}

// ---------------- qw = pool_w^T . pool_q  (512 outputs, f32) ----------------
__global__ __launch_bounds__(256) void k_poolq(const float* __restrict__ pq,
                                               const float* __restrict__ W,
                                               float* __restrict__ qw) {
    int d = blockIdx.x * 256 + threadIdx.x;
    float s = 0.f;
    for (int e = 0; e < 512; ++e) s += pq[e] * W[(size_t)e * 512 + d];
    qw[d] = s;
}

// ---------------- embed + ln1(l=0) fused: one block per sample ----------------
__global__ __launch_bounds__(256) void k_embed_ln(const float* __restrict__ x,
                                                  const float* __restrict__ be,
                                                  const float* __restrict__ w,
                                                  const float* __restrict__ b,
                                                  u16* __restrict__ Xb,
                                                  u16* __restrict__ Hb) {
    __shared__ u16 ld[4][512];
    int s = blockIdx.x;
    int tid = threadIdx.x;
    const float* xs = x + (size_t)s * 2048;
#pragma unroll
    for (int i = 0; i < 2; ++i) {
        int d = tid + i * 256;
        float4 v = *(const float4*)(xs + d * 4);
        ld[0][d] = f2bf(v.x + be[d]);
        ld[1][d] = f2bf(v.y + be[512 + d]);
        ld[2][d] = f2bf(v.z + be[1024 + d]);
        ld[3][d] = f2bf(v.w + be[1536 + d]);
    }
    __syncthreads();
    int t = tid >> 6, lane = tid & 63;
    u16x8 raw = *(const u16x8*)(&ld[t][lane * 8]);
    *(u16x8*)(Xb + ((size_t)s * 4 + t) * 512 + lane * 8) = raw;
    float a[8];
#pragma unroll
    for (int j = 0; j < 8; ++j) a[j] = bf2f(raw[j]);
    float s1 = 0.f, s2 = 0.f;
#pragma unroll
    for (int j = 0; j < 8; ++j) { s1 += a[j]; s2 += a[j] * a[j]; }
#pragma unroll
    for (int d = 1; d < 64; d <<= 1) { s1 += __shfl_xor(s1, d); s2 += __shfl_xor(s2, d); }
    float mean = s1 * (1.0f / 512.0f);
    float var  = s2 * (1.0f / 512.0f) - mean * mean;
    float rstd = rsqrtf(var + 1e-5f);
    float4 w0 = *(const float4*)(w + lane * 8);
    float4 w1 = *(const float4*)(w + lane * 8 + 4);
    float4 b0 = *(const float4*)(b + lane * 8);
    float4 b1 = *(const float4*)(b + lane * 8 + 4);
    float wv[8] = {w0.x, w0.y, w0.z, w0.w, w1.x, w1.y, w1.z, w1.w};
    float bv[8] = {b0.x, b0.y, b0.z, b0.w, b1.x, b1.y, b1.z, b1.w};
    u16x8 o;
#pragma unroll
    for (int j = 0; j < 8; ++j) o[j] = f2bf((a[j] - mean) * rstd * wv[j] + bv[j]);
    *(u16x8*)(Hb + ((size_t)s * 4 + t) * 512 + lane * 8) = o;
}

// ---------------- layernorm: bf16 row (512) -> bf16 row; wave per row ----------------
__global__ __launch_bounds__(256) void k_ln(const u16* __restrict__ Xb,
                                            const float* __restrict__ w,
                                            const float* __restrict__ b,
                                            u16* __restrict__ H) {
    int row = blockIdx.x * 4 + (threadIdx.x >> 6);
    int lane = threadIdx.x & 63;
    u16x8 xv = *(const u16x8*)(Xb + (size_t)row * 512 + lane * 8);
    float a[8];
#pragma unroll
    for (int j = 0; j < 8; ++j) a[j] = bf2f(xv[j]);
    float s1 = 0.f, s2 = 0.f;
#pragma unroll
    for (int j = 0; j < 8; ++j) { s1 += a[j]; s2 += a[j] * a[j]; }
#pragma unroll
    for (int d = 1; d < 64; d <<= 1) { s1 += __shfl_xor(s1, d); s2 += __shfl_xor(s2, d); }
    float mean = s1 * (1.0f / 512.0f);
    float var  = s2 * (1.0f / 512.0f) - mean * mean;
    float rstd = rsqrtf(var + 1e-5f);
    float4 w0 = *(const float4*)(w + lane * 8);
    float4 w1 = *(const float4*)(w + lane * 8 + 4);
    float4 b0 = *(const float4*)(b + lane * 8);
    float4 b1 = *(const float4*)(b + lane * 8 + 4);
    float wv[8] = {w0.x, w0.y, w0.z, w0.w, w1.x, w1.y, w1.z, w1.w};
    float bv[8] = {b0.x, b0.y, b0.z, b0.w, b1.x, b1.y, b1.z, b1.w};
    u16x8 o;
#pragma unroll
    for (int j = 0; j < 8; ++j) o[j] = f2bf((a[j] - mean) * rstd * wv[j] + bv[j]);
    *(u16x8*)(H + (size_t)row * 512 + lane * 8) = o;
}

// ---------------- GEMM: persistent 8-phase (cross-tile pipelined) ----------------
// 256x256 tile, BK=64, 8 waves, 2x64KB LDS bufs, persistent blocks.
// XCD-aware interleaved panel-sharing schedule (verified R2: FETCH ~ideal).
// RESID: bf16 RMW of Xb. BOUNCE+NT (QKV only; verified R1/R5): per-wave 2KB
// LDS bounce -> full-128B-line NT stores. NT is ONLY safe for outputs that
// are not the next GEMM's A operand (R7 lesson: NT on Fb forced ffn2's
// staging to HBM, +150us).
template <bool BIAS, bool GELU_, bool RESID, bool BOUNCE, bool NT>
__global__ __launch_bounds__(512, 2) void k_gemm256(const u16* __restrict__ A,
                                                    const u16* __restrict__ W,
                                                    const float* __restrict__ bias,
                                                    u16* __restrict__ Cb,
                                                    u16* __restrict__ Xbres,
                                                    int K, int ncols, int TN, int T) {
    __shared__ __align__(16) u16 lds[2 * 32768];
    __shared__ __align__(16) u16 bounce[8192];  // 16 KB: 2 KB per wave
    int tid = threadIdx.x;
    int lane = tid & 63;
    int wid = tid >> 6;
    int G = gridDim.x, b = blockIdx.x;
    int start, end, step;
    if ((G & 7) == 0) {
        int xcd = b & 7, nxb = G >> 3, j = b >> 3;
        start = (int)(((long long)xcd * T) >> 3) + j;
        end   = (int)(((long long)(xcd + 1) * T) >> 3);
        step  = nxb;
    } else {
        start = (int)(((long long)b * T) / G);
        end   = (int)(((long long)(b + 1) * T) / G);
        step  = 1;
    }
    if (start >= end) return;
    int NS = K >> 6;   // K-steps of 64, even (K in {512,1024})
    int mgrp = wid >> 2, ngrp = wid & 3;

    f32x4 acc[8][4];
#pragma unroll
    for (int i = 0; i < 8; ++i)
#pragma unroll
        for (int j = 0; j < 4; ++j) acc[i][j] = (f32x4){0.f, 0.f, 0.f, 0.f};

    int srow = tid >> 3;
    int sel  = (((tid & 7) * 16) ^ ((srow & 7) << 4)) >> 1;
    size_t K64 = (size_t)K * 64;
    char* ldsB = (char*)lds;
    int wdst = wid * 1024;

    const u16 *cA0, *cA1, *cB0, *cB1, *nA0, *nA1, *nB0, *nB1;
    int cm0, cn0, nm0, nn0;
    auto tilePtrs = [&](int ti, const u16*& a0, const u16*& a1,
                        const u16*& b0, const u16*& b1, int& m0o, int& n0o) {
        int bx = ti / TN, by = ti - bx * TN;
        int m0 = bx * 256, n0 = by * 256;
        a0 = A + (size_t)(m0 + srow) * K + sel;
        a1 = A + (size_t)(m0 + 128 + srow) * K + sel;
        b0 = W + (size_t)(n0 + srow) * K + sel;
        b1 = W + (size_t)(n0 + 128 + srow) * K + sel;
        m0o = m0; n0o = n0;
    };

    auto S_Aq12 = [&](const u16* a0, const u16* a1, int s) {
        char* d = ldsB + (s & 1) * 65536 + wdst;
        gload16(a0 + (size_t)s * 64, d);
        gload16(a1 + (size_t)s * 64, d + 16384);
    };
    auto S_Aq34 = [&](const u16* a0, const u16* a1, int s) {
        char* d = ldsB + (s & 1) * 65536 + 8192 + wdst;
        gload16(a0 + K64 + (size_t)s * 64, d);
        gload16(a1 + K64 + (size_t)s * 64, d + 16384);
    };
    auto S_Blo = [&](const u16* b0, int s) {
        char* d = ldsB + (s & 1) * 65536 + 32768 + wdst;
        gload16(b0 + (size_t)s * 64, d);
        gload16(b0 + K64 + (size_t)s * 64, d + 8192);
    };
    auto S_Bhi = [&](const u16* b1, int s) {
        char* d = ldsB + (s & 1) * 65536 + 49152 + wdst;
        gload16(b1 + (size_t)s * 64, d);
        gload16(b1 + K64 + (size_t)s * 64, d + 8192);
    };

    int arow = mgrp * 128 + (lane & 15);
    int brow = ngrp * 64 + (lane & 15);
    int sub = (lane >> 4) << 4;
    int amask = ((arow & 7) << 4), bmask = ((brow & 7) << 4);
    int aoff0 = arow * 128 + (sub ^ amask);
    int boff0 = 32768 + brow * 128 + (sub ^ bmask);
    int aoff1 = arow * 128 + ((sub | 64) ^ amask);
    int boff1 = 32768 + brow * 128 + ((sub | 64) ^ bmask);

    tilePtrs(start, cA0, cA1, cB0, cB1, cm0, cn0);
    S_Blo(cB0, 0); S_Bhi(cB1, 0); S_Aq12(cA0, cA1, 0); S_Aq34(cA0, cA1, 0);
    S_Blo(cB0, 1); S_Bhi(cB1, 1); S_Aq12(cA0, cA1, 1);
    asm volatile("s_waitcnt vmcnt(6)" ::: "memory");
    __builtin_amdgcn_s_barrier();

    for (int ti = start; ti < end; ti += step) {
        bool hasNext = (ti + step < end);
        if (hasNext) tilePtrs(ti + step, nA0, nA1, nB0, nB1, nm0, nn0);

        s16x8 bfr[4][2];
        for (int s = 0; s < NS; ++s) {
            const char* sb = ldsB + (s & 1) * 65536;
            int st = s + 1, st2 = s + 2;
            bool n1 = st < NS, n2 = st2 < NS;
            // ---------- phase 1 ----------
            s16x8 af[2][2];
#pragma unroll
            for (int ni = 0; ni < 4; ++ni) {
                bfr[ni][0] = *(const s16x8*)(sb + boff0 + ni * 2048);
                bfr[ni][1] = *(const s16x8*)(sb + boff1 + ni * 2048);
            }
            af[0][0] = *(const s16x8*)(sb + aoff0);
            af[0][1] = *(const s16x8*)(sb + aoff1);
            af[1][0] = *(const s16x8*)(sb + aoff0 + 2048);
            af[1][1] = *(const s16x8*)(sb + aoff1 + 2048);
            if (n1) S_Aq34(cA0, cA1, st); else if (hasNext) S_Aq34(nA0, nA1, st - NS);
            __builtin_amdgcn_s_barrier();
            __builtin_amdgcn_s_setprio(1);
#pragma unroll
            for (int mj = 0; mj < 2; ++mj)
#pragma unroll
                for (int ni = 0; ni < 4; ++ni) {
                    acc[mj][ni] = __builtin_amdgcn_mfma_f32_16x16x32_bf16(bfr[ni][0], af[mj][0], acc[mj][ni], 0, 0, 0);
                    acc[mj][ni] = __builtin_amdgcn_mfma_f32_16x16x32_bf16(bfr[ni][1], af[mj][1], acc[mj][ni], 0, 0, 0);
                }
            __builtin_amdgcn_s_setprio(0);
            __builtin_amdgcn_s_barrier();
            // ---------- phase 2 ----------
#pragma unroll
            for (int mj = 0; mj < 2; ++mj) {
                af[mj][0] = *(const s16x8*)(sb + aoff0 + (2 + mj) * 2048);
                af[mj][1] = *(const s16x8*)(sb + aoff1 + (2 + mj) * 2048);
            }
            if (n2) S_Blo(cB0, st2); else if (hasNext) S_Blo(nB0, st2 - NS);
            __builtin_amdgcn_s_barrier();
            __builtin_amdgcn_s_setprio(1);
#pragma unroll
            for (int mj = 0; mj < 2; ++mj)
#pragma unroll
                for (int ni = 0; ni < 4; ++ni) {
                    acc[2 + mj][ni] = __builtin_amdgcn_mfma_f32_16x16x32_bf16(bfr[ni][0], af[mj][0], acc[2 + mj][ni], 0, 0, 0);
                    acc[2 + mj][ni] = __builtin_amdgcn_mfma_f32_16x16x32_bf16(bfr[ni][1], af[mj][1], acc[2 + mj][ni], 0, 0, 0);
                }
            __builtin_amdgcn_s_setprio(0);
            __builtin_amdgcn_s_barrier();
            // ---------- phase 3 ----------
#pragma unroll
            for (int mj = 0; mj < 2; ++mj) {
                af[mj][0] = *(const s16x8*)(sb + aoff0 + (4 + mj) * 2048);
                af[mj][1] = *(const s16x8*)(sb + aoff1 + (4 + mj) * 2048);
            }
            if (n2) S_Bhi(cB1, st2); else if (hasNext) S_Bhi(nB1, st2 - NS);
            __builtin_amdgcn_s_barrier();
            __builtin_amdgcn_s_setprio(1);
#pragma unroll
            for (int mj = 0; mj < 2; ++mj)
#pragma unroll
                for (int ni = 0; ni < 4; ++ni) {
                    acc[4 + mj][ni] = __builtin_amdgcn_mfma_f32_16x16x32_bf16(bfr[ni][0], af[mj][0], acc[4 + mj][ni], 0, 0, 0);
                    acc[4 + mj][ni] = __builtin_amdgcn_mfma_f32_16x16x32_bf16(bfr[ni][1], af[mj][1], acc[4 + mj][ni], 0, 0, 0);
                }
            __builtin_amdgcn_s_setprio(0);
            __builtin_amdgcn_s_barrier();
            // ---------- phase 4 ----------
#pragma unroll
            for (int mj = 0; mj < 2; ++mj) {
                af[mj][0] = *(const s16x8*)(sb + aoff0 + (6 + mj) * 2048);
                af[mj][1] = *(const s16x8*)(sb + aoff1 + (6 + mj) * 2048);
            }
            if (n2) S_Aq12(cA0, cA1, st2); else if (hasNext) S_Aq12(nA0, nA1, st2 - NS);
            __builtin_amdgcn_s_barrier();
            __builtin_amdgcn_s_setprio(1);
#pragma unroll
            for (int mj = 0; mj < 2; ++mj)
#pragma unroll
                for (int ni = 0; ni < 4; ++ni) {
                    acc[6 + mj][ni] = __builtin_amdgcn_mfma_f32_16x16x32_bf16(bfr[ni][0], af[mj][0], acc[6 + mj][ni], 0, 0, 0);
                    acc[6 + mj][ni] = __builtin_amdgcn_mfma_f32_16x16x32_bf16(bfr[ni][1], af[mj][1], acc[6 + mj][ni], 0, 0, 0);
                }
            __builtin_amdgcn_s_setprio(0);
            bool staged24 = n2 || hasNext;
            bool last = (s == NS - 1) && !hasNext;
            if (!last) {
                if (staged24) asm volatile("s_waitcnt vmcnt(6)" ::: "memory");
                else          asm volatile("s_waitcnt vmcnt(0)" ::: "memory");
                __builtin_amdgcn_s_barrier();
            }
        }

        // ---- epilogue for tile ti ----
        int r_lane = lane & 15, cg = lane >> 4;
        float4 bb[4];
        if (BIAS) {
#pragma unroll
            for (int ni = 0; ni < 4; ++ni)
                bb[ni] = *(const float4*)(bias + cn0 + ngrp * 64 + ni * 16 + cg * 4);
        }
        if (BOUNCE) {
            u16* bw = bounce + wid * 1024;
            int qrow = lane >> 3, kc = lane & 7;
#pragma unroll
            for (int mi = 0; mi < 8; ++mi) {
                int rowbase = cm0 + mgrp * 128 + mi * 16;
#pragma unroll
                for (int ni = 0; ni < 4; ++ni) {
                    f32x4 v = acc[mi][ni];
                    if (BIAS) { v[0] += bb[ni].x; v[1] += bb[ni].y; v[2] += bb[ni].z; v[3] += bb[ni].w; }
                    if (GELU_) {
#pragma unroll
                        for (int j = 0; j < 4; ++j) v[j] = gelu_exact(v[j]);
                    }
                    uint2 o;
                    o.x = (u32)f2bf(v[0]) | ((u32)f2bf(v[1]) << 16);
                    o.y = (u32)f2bf(v[2]) | ((u32)f2bf(v[3]) << 16);
                    int slot = (4 * ni + cg) ^ (r_lane & 14);
                    *(uint2*)(bw + r_lane * 64 + slot * 4) = o;
                    acc[mi][ni] = (f32x4){0.f, 0.f, 0.f, 0.f};
                }
                asm volatile("s_waitcnt lgkmcnt(0)" ::: "memory");
#pragma unroll
                for (int h = 0; h < 2; ++h) {
                    int rd = h * 8 + qrow;
                    int e = (2 * kc) ^ (rd & 14);
                    u32x4 t = *(const u32x4*)(bw + rd * 64 + e * 4);
                    int row = rowbase + rd;
                    int c2 = cn0 + ngrp * 64 + kc * 8;
                    u16* dst = Cb + (size_t)row * ncols + c2;
                    if (NT) __builtin_nontemporal_store(t, (u32x4*)dst);
                    else    *(u32x4*)dst = t;
                }
                asm volatile("s_waitcnt lgkmcnt(0)" ::: "memory");
            }
        } else {
#pragma unroll
            for (int mi = 0; mi < 8; ++mi) {
                int row = cm0 + mgrp * 128 + mi * 16 + r_lane;
#pragma unroll
                for (int ni = 0; ni < 4; ++ni) {
                    int c = cn0 + ngrp * 64 + ni * 16 + cg * 4;
                    f32x4 v = acc[mi][ni];
                    if (BIAS) { v[0] += bb[ni].x; v[1] += bb[ni].y; v[2] += bb[ni].z; v[3] += bb[ni].w; }
                    if (GELU_) {
#pragma unroll
                        for (int j = 0; j < 4; ++j) v[j] = gelu_exact(v[j]);
                    }
                    if (RESID) {
                        u16* px = Xbres + (size_t)row * 512 + c;
                        uint2 xv = *(uint2*)px;
                        float x0 = bflo(xv.x) + v[0];
                        float x1 = bfhi(xv.x) + v[1];
                        float x2 = bflo(xv.y) + v[2];
                        float x3 = bfhi(xv.y) + v[3];
                        uint2 o;
                        o.x = (u32)f2bf(x0) | ((u32)f2bf(x1) << 16);
                        o.y = (u32)f2bf(x2) | ((u32)f2bf(x3) << 16);
                        *(uint2*)px = o;
                    } else {
                        u32 lo = (u32)f2bf(v[0]) | ((u32)f2bf(v[1]) << 16);
                        u32 hi = (u32)f2bf(v[2]) | ((u32)f2bf(v[3]) << 16);
                        uint2 o; o.x = lo; o.y = hi;
                        *(uint2*)(Cb + (size_t)row * ncols + c) = o;
                    }
                    acc[mi][ni] = (f32x4){0.f, 0.f, 0.f, 0.f};
                }
            }
        }
        cA0 = nA0; cA1 = nA1; cB0 = nB0; cB1 = nB1; cm0 = nm0; cn0 = nn0;
    }
}

// ---------------- attention: T=4, per (sample, head) per wave ----------------
__global__ __launch_bounds__(256) void k_attn(const u16* __restrict__ QKV, u16* __restrict__ O) {
    int task = blockIdx.x * 4 + (threadIdx.x >> 6);
    int lane = threadIdx.x & 63;
    int s = task >> 2, h = task & 3;
    const u16* base = QKV + (size_t)s * 4 * 1536 + h * 128;
    float q[4][2], k[4][2], v[4][2];
#pragma unroll
    for (int t = 0; t < 4; ++t) {
        const u16* row = base + t * 1536;
        u32 uq = *(const u32*)(row + lane * 2);
        u32 uk = *(const u32*)(row + 512 + lane * 2);
        u32 uv = *(const u32*)(row + 1024 + lane * 2);
        q[t][0] = bflo(uq); q[t][1] = bfhi(uq);
        k[t][0] = bflo(uk); k[t][1] = bfhi(uk);
        v[t][0] = bflo(uv); v[t][1] = bfhi(uv);
    }
    float sc[4][4];
#pragma unroll
    for (int i = 0; i < 4; ++i)
#pragma unroll
        for (int j = 0; j < 4; ++j) {
            float p = q[i][0] * k[j][0] + q[i][1] * k[j][1];
#pragma unroll
            for (int d = 1; d < 64; d <<= 1) p += __shfl_xor(p, d);
            sc[i][j] = p * 0.08838834764831845f;  // 1/sqrt(128)
        }
    float o[4][2];
#pragma unroll
    for (int i = 0; i < 4; ++i) {
        float mx = fmaxf(fmaxf(sc[i][0], sc[i][1]), fmaxf(sc[i][2], sc[i][3]));
        float e0 = expf(sc[i][0] - mx), e1 = expf(sc[i][1] - mx);
        float e2 = expf(sc[i][2] - mx), e3 = expf(sc[i][3] - mx);
        float inv = 1.0f / (e0 + e1 + e2 + e3);
        float a0 = e0 * inv, a1 = e1 * inv, a2 = e2 * inv, a3 = e3 * inv;
        o[i][0] = a0 * v[0][0] + a1 * v[1][0] + a2 * v[2][0] + a3 * v[3][0];
        o[i][1] = a0 * v[0][1] + a1 * v[1][1] + a2 * v[2][1] + a3 * v[3][1];
    }
#pragma unroll
    for (int i = 0; i < 4; ++i) {
        u32 pk = (u32)f2bf(o[i][0]) | ((u32)f2bf(o[i][1]) << 16);
        *(u32*)(O + ((size_t)s * 4 + i) * 512 + h * 128 + lane * 2) = pk;
    }
}

// ---------------- pooling: score via qw, z, out-LN -> Zb bf16 ; wave per sample ----------------
__global__ __launch_bounds__(256) void k_pool(const u16* __restrict__ Xb, const float* __restrict__ qw,
                                              const float* __restrict__ olnw, const float* __restrict__ olnb,
                                              u16* __restrict__ Zb) {
    int s = blockIdx.x * 4 + (threadIdx.x >> 6);
    int lane = threadIdx.x & 63;
    float4 q0 = *(const float4*)(qw + lane * 8);
    float4 q1 = *(const float4*)(qw + lane * 8 + 4);
    float qv[8] = {q0.x, q0.y, q0.z, q0.w, q1.x, q1.y, q1.z, q1.w};
    u16x8 xr[4];
    float dot[4];
#pragma unroll
    for (int t = 0; t < 4; ++t) {
        xr[t] = *(const u16x8*)(Xb + ((size_t)s * 4 + t) * 512 + lane * 8);
        float p = 0.f;
#pragma unroll
        for (int j = 0; j < 8; ++j) p += qv[j] * bf2f(xr[t][j]);
#pragma unroll
        for (int d = 1; d < 64; d <<= 1) p += __shfl_xor(p, d);
        dot[t] = p * 0.044194173824159216f;  // 1/sqrt(512)
    }
    float mx = fmaxf(fmaxf(dot[0], dot[1]), fmaxf(dot[2], dot[3]));
    float e[4], se = 0.f;
#pragma unroll
    for (int t = 0; t < 4; ++t) { e[t] = expf(dot[t] - mx); se += e[t]; }
    float inv = 1.0f / se;
    float z[8] = {0, 0, 0, 0, 0, 0, 0, 0};
#pragma unroll
    for (int t = 0; t < 4; ++t) {
        float scv = e[t] * inv;
#pragma unroll
        for (int j = 0; j < 8; ++j) z[j] += scv * bf2f(xr[t][j]);
    }
    float s1 = 0.f, s2 = 0.f;
#pragma unroll
    for (int j = 0; j < 8; ++j) { s1 += z[j]; s2 += z[j] * z[j]; }
#pragma unroll
    for (int d = 1; d < 64; d <<= 1) { s1 += __shfl_xor(s1, d); s2 += __shfl_xor(s2, d); }
    float mean = s1 * (1.0f / 512.0f);
    float var  = s2 * (1.0f / 512.0f) - mean * mean;
    float rstd = rsqrtf(var + 1e-5f);
    float4 w0 = *(const float4*)(olnw + lane * 8);
    float4 w1 = *(const float4*)(olnw + lane * 8 + 4);
    float4 b0 = *(const float4*)(olnb + lane * 8);
    float4 b1 = *(const float4*)(olnb + lane * 8 + 4);
    float wv[8] = {w0.x, w0.y, w0.z, w0.w, w1.x, w1.y, w1.z, w1.w};
    float bv[8] = {b0.x, b0.y, b0.z, b0.w, b1.x, b1.y, b1.z, b1.w};
    u16x8 o;
#pragma unroll
    for (int j = 0; j < 8; ++j) o[j] = f2bf((z[j] - mean) * rstd * wv[j] + bv[j]);
    *(u16x8*)(Zb + (size_t)s * 512 + lane * 8) = o;
}

// ---------------- final: y = G(s,256) . w2 + b2 ; wave per sample ----------------
__global__ __launch_bounds__(256) void k_out2(const u16* __restrict__ G, const float* __restrict__ w2,
                                              const float* __restrict__ b2, float* __restrict__ y) {
    int s = blockIdx.x * 4 + (threadIdx.x >> 6);
    int lane = threadIdx.x & 63;
    uint2 u = *(const uint2*)(G + (size_t)s * 256 + lane * 4);
    float4 wv = *(const float4*)(w2 + lane * 4);
    float p = bflo(u.x) * wv.x + bfhi(u.x) * wv.y + bflo(u.y) * wv.z + bfhi(u.y) * wv.w;
#pragma unroll
    for (int d = 1; d < 64; d <<= 1) p += __shfl_xor(p, d);
    if (lane == 0) y[s] = p + b2[0];
}

extern "C" void kernel_launch(void* const* d_in, const int* in_sizes, int n_in,
                              void* d_out, int out_size, void* d_ws, size_t ws_size,
                              hipStream_t stream) {
    const float* x     = (const float*)d_in[0];
    const float* be    = (const float*)d_in[1];
    const float* ln1w  = (const float*)d_in[2];
    const float* ln1b  = (const float*)d_in[3];
    const float* qkvw  = (const float*)d_in[4];
    const float* qkvb  = (const float*)d_in[5];
    const float* projw = (const float*)d_in[6];
    const float* projb = (const float*)d_in[7];
    const float* ln2w  = (const float*)d_in[8];
    const float* ln2b  = (const float*)d_in[9];
    const float* f1w   = (const float*)d_in[10];
    const float* f1b   = (const float*)d_in[11];
    const float* f2w   = (const float*)d_in[12];
    const float* f2b   = (const float*)d_in[13];
    const float* poolq = (const float*)d_in[14];
    const float* poolw = (const float*)d_in[15];
    const float* olnw  = (const float*)d_in[16];
    const float* olnb  = (const float*)d_in[17];
    const float* ow1   = (const float*)d_in[18];
    const float* ob1   = (const float*)d_in[19];
    const float* ow2   = (const float*)d_in[20];
    const float* ob2   = (const float*)d_in[21];
    float* y = (float*)d_out;

    int N = in_sizes[0] / 2048;  // (N,512,4)

    char* p = (char*)d_ws;
    auto take = [&](size_t b) { char* r = p; p += (b + 255) & ~(size_t)255; return r; };
    u16* qkvWb  = (u16*)take((size_t)3145728 * 2);
    u16* projWb = (u16*)take((size_t)1048576 * 2);
    u16* f1Wb   = (u16*)take((size_t)2097152 * 2);
    u16* f2Wb   = (u16*)take((size_t)2097152 * 2);
    u16* ow1b   = (u16*)take((size_t)131072 * 2);
    float* qw   = (float*)take(512 * 4);
    size_t fixedB = (size_t)(p - (char*)d_ws);

    // single chunk; halve only if ws_size forces it.
    int S = N;
    while (S > 256 && fixedB + (size_t)S * 20480 + 65536 > ws_size) S >>= 1;
    int R = S * 4;
    int TM = R / 256;

    u16* Xb    = (u16*)take((size_t)R * 512 * 2);   // persistent bf16 X
    u16* Hb    = (u16*)take((size_t)R * 512 * 2);
    u16* QKVb  = (u16*)take((size_t)R * 1536 * 2);
    u16* Fb  = QKVb;                                   // R x 1024 (FFN phase)
    u16* Gb  = (u16*)((char*)QKVb + (size_t)R * 512 * 2);  // S x 256 (head phase)
    u16* Zb  = Hb;

    // merged weight-convert (5 tensors) + pool-query projection
    k_cvt5<<<8320, 256, 0, stream>>>(qkvw, qkvWb, projw, projWb, f1w, f1Wb,
                                     f2w, f2Wb, ow1, ow1b);
    k_poolq<<<2, 256, 0, stream>>>(poolq, poolw, qw);

    auto gridFor = [](int T) { return T < 256 ? T : 256; };

    for (int c0 = 0; c0 < N; c0 += S) {
        const float* xin = x + (size_t)c0 * 2048;
        k_embed_ln<<<S, 256, 0, stream>>>(xin, be, ln1w, ln1b, Xb, Hb);
        for (int l = 0; l < 4; ++l) {
            if (l > 0)
                k_ln<<<R / 4, 256, 0, stream>>>(Xb, ln1w + l * 512, ln1b + l * 512, Hb);
            { int T = TM * 6;   // QKV: bias, bounce+NT (QKVb not a GEMM operand next)
              k_gemm256<true, false, false, true, true><<<gridFor(T), 512, 0, stream>>>(
                  Hb, qkvWb + (size_t)l * 786432, qkvb + l * 1536, QKVb, nullptr, 512, 1536, 6, T); }
            k_attn<<<S, 256, 0, stream>>>(QKVb, Hb);
            { int T = TM * 2;   // proj: resid RMW
              k_gemm256<true, false, true, false, false><<<gridFor(T), 512, 0, stream>>>(
                  Hb, projWb + (size_t)l * 262144, projb + l * 512, nullptr, Xb, 512, 512, 2, T); }
            k_ln<<<R / 4, 256, 0, stream>>>(Xb, ln2w + l * 512, ln2b + l * 512, Hb);
            { int T = TM * 4;   // ffn1: bias+gelu, plain stores (Fb is ffn2's A operand)
              k_gemm256<true, true, false, false, false><<<gridFor(T), 512, 0, stream>>>(
                  Hb, f1Wb + (size_t)l * 524288, f1b + l * 1024, Fb, nullptr, 512, 1024, 4, T); }
            { int T = TM * 2;   // ffn2: resid RMW
              k_gemm256<true, false, true, false, false><<<gridFor(T), 512, 0, stream>>>(
                  Fb, f2Wb + (size_t)l * 524288, f2b + l * 512, nullptr, Xb, 1024, 512, 2, T); }
        }
        k_pool<<<S / 4, 256, 0, stream>>>(Xb, qw, olnw, olnb, Zb);
        { int T = S / 256;
          k_gemm256<true, true, false, false, false><<<gridFor(T), 512, 0, stream>>>(
              Zb, ow1b, ob1, Gb, nullptr, 512, 256, 1, T); }
        k_out2<<<S / 4, 256, 0, stream>>>(Gb, ow2, ob2, y + c0);
    }
    (void)n_in; (void)out_size; (void)ws_size;
}

// Round 9
// 3946.634 us; speedup vs baseline: 1.1847x; 1.0867x over previous
//
#include <hip/hip_runtime.h>

typedef unsigned short u16;
typedef unsigned int u32;
typedef __attribute__((ext_vector_type(8))) short s16x8;
typedef __attribute__((ext_vector_type(8))) unsigned short u16x8;
typedef __attribute__((ext_vector_type(4))) float f32x4;
typedef __attribute__((ext_vector_type(4))) unsigned int u32x4;

__device__ __forceinline__ u16 f2bf(float f) {
    u32 u = __float_as_uint(f);
    u32 r = (u + 0x7fffu + ((u >> 16) & 1u)) >> 16;
    return (u16)r;
}
__device__ __forceinline__ float bf2f(u16 u) { return __uint_as_float(((u32)u) << 16); }
__device__ __forceinline__ float bflo(u32 u) { return __uint_as_float(u << 16); }
__device__ __forceinline__ float bfhi(u32 u) { return __uint_as_float(u & 0xffff0000u); }
__device__ __forceinline__ float gelu_exact(float v) {
    return 0.5f * v * (1.0f + erff(v * 0.70710678118654752f));
}

// async global -> LDS, 16B per lane. LDS dest = wave-uniform base + lane*16.
__device__ __forceinline__ void gload16(const void* g, void* l) {
    __builtin_amdgcn_global_load_lds(
        (const __attribute__((address_space(1))) u32*)g,
        (__attribute__((address_space(3))) u32*)l, 16, 0, 0);
}

// ---------------- fp32 -> bf16 convert: 5 weight tensors; LN-gamma folded into qkv/f1 ----------------
__global__ __launch_bounds__(256) void k_cvt5(const float* __restrict__ s0, u16* __restrict__ d0,
                                              const float* __restrict__ g0,
                                              const float* __restrict__ s1, u16* __restrict__ d1,
                                              const float* __restrict__ s2, u16* __restrict__ d2,
                                              const float* __restrict__ g2,
                                              const float* __restrict__ s3, u16* __restrict__ d3,
                                              const float* __restrict__ s4, u16* __restrict__ d4) {
    int i = blockIdx.x * 256 + threadIdx.x;
    const float* s; u16* d; int off; const float* gm = nullptr; int gidx = 0;
    if (i < 786432)       { s = s0; d = d0; off = i; gm = g0; gidx = (off / 196608) * 512 + (off & 127) * 4; }
    else if (i < 1048576) { s = s1; d = d1; off = i - 786432; }
    else if (i < 1572864) { s = s2; d = d2; off = i - 1048576; gm = g2; gidx = (off / 131072) * 512 + (off & 127) * 4; }
    else if (i < 2097152) { s = s3; d = d3; off = i - 1572864; }
    else                  { s = s4; d = d4; off = i - 2097152; }
    float4 v = *(const float4*)(s + (size_t)off * 4);
    if (gm) {
        float4 g = *(const float4*)(gm + gidx);
        v.x *= g.x; v.y *= g.y; v.z *= g.z; v.w *= g.w;
    }
    u16 o0 = f2bf(v.x), o1 = f2bf(v.y), o2 = f2bf(v.z), o3 = f2bf(v.w);
    uint2 o; o.x = (u32)o0 | ((u32)o1 << 16); o.y = (u32)o2 | ((u32)o3 << 16);
    *(uint2*)(d + (size_t)off * 4) = o;
}

// ---------------- u[c] = sum_k W'(bf16)[c,k] ; b2[c] = bias[c] + sum_k beta_k * Wf32[c,k] ----------------
// one wave per output channel c; qkv (4x1536) then ffn1 (4x1024).
__global__ __launch_bounds__(256) void k_uv(const u16* __restrict__ Wq, const float* __restrict__ Wqf,
                                            const float* __restrict__ bq, const float* __restrict__ betaq,
                                            float* __restrict__ uq, float* __restrict__ b2q,
                                            const u16* __restrict__ Wf, const float* __restrict__ Wff,
                                            const float* __restrict__ bf_, const float* __restrict__ betaf,
                                            float* __restrict__ uf, float* __restrict__ b2f) {
    int wid = blockIdx.x * 4 + (threadIdx.x >> 6);
    int lane = threadIdx.x & 63;
    const u16* wrow; const float* frow; const float* beta; float bias0; float* up; float* b2p; int idx;
    if (wid < 6144) {
        int l = wid / 1536, c = wid - l * 1536;
        size_t ro = ((size_t)l * 1536 + c) * 512;
        wrow = Wq + ro; frow = Wqf + ro; beta = betaq + l * 512;
        bias0 = bq[l * 1536 + c]; up = uq; b2p = b2q; idx = wid;
    } else {
        int w2 = wid - 6144;
        int l = w2 / 1024, c = w2 - l * 1024;
        size_t ro = ((size_t)l * 1024 + c) * 512;
        wrow = Wf + ro; frow = Wff + ro; beta = betaf + l * 512;
        bias0 = bf_[l * 1024 + c]; up = uf; b2p = b2f; idx = w2;
    }
    float su = 0.f, sb = 0.f;
#pragma unroll
    for (int j = 0; j < 8; ++j) {
        int k = lane * 8 + j;
        su += bf2f(wrow[k]);
        sb += beta[k] * frow[k];
    }
#pragma unroll
    for (int d = 1; d < 64; d <<= 1) { su += __shfl_xor(su, d); sb += __shfl_xor(sb, d); }
    if (lane == 0) { up[idx] = su; b2p[idx] = bias0 + sb; }
}

// ---------------- qw = pool_w^T . pool_q  (512 outputs, f32) ----------------
__global__ __launch_bounds__(256) void k_poolq(const float* __restrict__ pq,
                                               const float* __restrict__ W,
                                               float* __restrict__ qw) {
    int d = blockIdx.x * 256 + threadIdx.x;
    float s = 0.f;
    for (int e = 0; e < 512; ++e) s += pq[e] * W[(size_t)e * 512 + d];
    qw[d] = s;
}

// ---------------- embed: x + branch_embed -> bf16 Xb, and row stats -> S1 ----------------
__global__ __launch_bounds__(256) void k_embed(const float* __restrict__ x,
                                               const float* __restrict__ be,
                                               u16* __restrict__ Xb,
                                               float2* __restrict__ S1) {
    __shared__ u16 ld[4][512];
    int s = blockIdx.x;
    int tid = threadIdx.x;
    const float* xs = x + (size_t)s * 2048;
#pragma unroll
    for (int i = 0; i < 2; ++i) {
        int d = tid + i * 256;
        float4 v = *(const float4*)(xs + d * 4);
        ld[0][d] = f2bf(v.x + be[d]);
        ld[1][d] = f2bf(v.y + be[512 + d]);
        ld[2][d] = f2bf(v.z + be[1024 + d]);
        ld[3][d] = f2bf(v.w + be[1536 + d]);
    }
    __syncthreads();
    int t = tid >> 6, lane = tid & 63;
    u16x8 raw = *(const u16x8*)(&ld[t][lane * 8]);
    *(u16x8*)(Xb + ((size_t)s * 4 + t) * 512 + lane * 8) = raw;
    float a[8];
#pragma unroll
    for (int j = 0; j < 8; ++j) a[j] = bf2f(raw[j]);
    float s1 = 0.f, s2 = 0.f;
#pragma unroll
    for (int j = 0; j < 8; ++j) { s1 += a[j]; s2 += a[j] * a[j]; }
#pragma unroll
    for (int d = 1; d < 64; d <<= 1) { s1 += __shfl_xor(s1, d); s2 += __shfl_xor(s2, d); }
    if (lane == 0) S1[(size_t)s * 4 + t] = (float2){s1, s2};
}

// ---------------- GEMM: persistent 8-phase (cross-tile pipelined) ----------------
// 256x256 tile, BK=64, 8 waves, 2x64KB LDS bufs, persistent blocks.
// XCD-aware interleaved panel-sharing schedule (verified R2: FETCH ~ideal).
// RESID: bf16 RMW of Xb. BOUNCE+NT (QKV only; verified R1/R5). NT only for
// outputs that are not the next GEMM's A operand (R7 lesson).
// LNIN: A is raw Xb; LN folded as out = rho_r*acc - mu_r*rho_r*u[c] + b2[c]
// (gamma pre-folded into W'; u = sum_k W'; exact identity). Reads stats Sin,
// zeroes the OTHER stats buffer Sout at entry (next RESID fills it).
// STATS: RESID epilogue accumulates per-row (sum,sumsq) of rounded residual
// into Sout via atomics (replaces the k_ln stats pass entirely).
template <bool BIAS, bool GELU_, bool RESID, bool BOUNCE, bool NT, bool LNIN, bool STATS>
__global__ __launch_bounds__(512, 2) void k_gemm256(const u16* __restrict__ A,
                                                    const u16* __restrict__ W,
                                                    const float* __restrict__ bias,
                                                    u16* __restrict__ Cb,
                                                    u16* __restrict__ Xbres,
                                                    const float2* __restrict__ Sin,
                                                    float* __restrict__ Sout,
                                                    const float* __restrict__ uvec,
                                                    int K, int ncols, int TN, int T, int R) {
    __shared__ __align__(16) u16 lds[2 * 32768];
    __shared__ __align__(16) u16 bounce[8192];  // 16 KB: 2 KB per wave
    int tid = threadIdx.x;
    int lane = tid & 63;
    int wid = tid >> 6;
    int G = gridDim.x, b = blockIdx.x;
    if (LNIN) {  // zero the stats buffer the next RESID GEMM will accumulate into
        float2* Sz = (float2*)Sout;
        for (int i = b * 512 + tid; i < R; i += G * 512)
            Sz[i] = (float2){0.f, 0.f};
    }
    int start, end, step;
    if ((G & 7) == 0) {
        int xcd = b & 7, nxb = G >> 3, j = b >> 3;
        start = (int)(((long long)xcd * T) >> 3) + j;
        end   = (int)(((long long)(xcd + 1) * T) >> 3);
        step  = nxb;
    } else {
        start = (int)(((long long)b * T) / G);
        end   = (int)(((long long)(b + 1) * T) / G);
        step  = 1;
    }
    if (start >= end) return;
    int NS = K >> 6;   // K-steps of 64, even (K in {512,1024})
    int mgrp = wid >> 2, ngrp = wid & 3;

    f32x4 acc[8][4];
#pragma unroll
    for (int i = 0; i < 8; ++i)
#pragma unroll
        for (int j = 0; j < 4; ++j) acc[i][j] = (f32x4){0.f, 0.f, 0.f, 0.f};

    int srow = tid >> 3;
    int sel  = (((tid & 7) * 16) ^ ((srow & 7) << 4)) >> 1;
    size_t K64 = (size_t)K * 64;
    char* ldsB = (char*)lds;
    int wdst = wid * 1024;

    const u16 *cA0, *cA1, *cB0, *cB1, *nA0, *nA1, *nB0, *nB1;
    int cm0, cn0, nm0, nn0;
    auto tilePtrs = [&](int ti, const u16*& a0, const u16*& a1,
                        const u16*& b0, const u16*& b1, int& m0o, int& n0o) {
        int bx = ti / TN, by = ti - bx * TN;
        int m0 = bx * 256, n0 = by * 256;
        a0 = A + (size_t)(m0 + srow) * K + sel;
        a1 = A + (size_t)(m0 + 128 + srow) * K + sel;
        b0 = W + (size_t)(n0 + srow) * K + sel;
        b1 = W + (size_t)(n0 + 128 + srow) * K + sel;
        m0o = m0; n0o = n0;
    };

    auto S_Aq12 = [&](const u16* a0, const u16* a1, int s) {
        char* d = ldsB + (s & 1) * 65536 + wdst;
        gload16(a0 + (size_t)s * 64, d);
        gload16(a1 + (size_t)s * 64, d + 16384);
    };
    auto S_Aq34 = [&](const u16* a0, const u16* a1, int s) {
        char* d = ldsB + (s & 1) * 65536 + 8192 + wdst;
        gload16(a0 + K64 + (size_t)s * 64, d);
        gload16(a1 + K64 + (size_t)s * 64, d + 16384);
    };
    auto S_Blo = [&](const u16* b0, int s) {
        char* d = ldsB + (s & 1) * 65536 + 32768 + wdst;
        gload16(b0 + (size_t)s * 64, d);
        gload16(b0 + K64 + (size_t)s * 64, d + 8192);
    };
    auto S_Bhi = [&](const u16* b1, int s) {
        char* d = ldsB + (s & 1) * 65536 + 49152 + wdst;
        gload16(b1 + (size_t)s * 64, d);
        gload16(b1 + K64 + (size_t)s * 64, d + 8192);
    };

    int arow = mgrp * 128 + (lane & 15);
    int brow = ngrp * 64 + (lane & 15);
    int sub = (lane >> 4) << 4;
    int amask = ((arow & 7) << 4), bmask = ((brow & 7) << 4);
    int aoff0 = arow * 128 + (sub ^ amask);
    int boff0 = 32768 + brow * 128 + (sub ^ bmask);
    int aoff1 = arow * 128 + ((sub | 64) ^ amask);
    int boff1 = 32768 + brow * 128 + ((sub | 64) ^ bmask);

    tilePtrs(start, cA0, cA1, cB0, cB1, cm0, cn0);
    S_Blo(cB0, 0); S_Bhi(cB1, 0); S_Aq12(cA0, cA1, 0); S_Aq34(cA0, cA1, 0);
    S_Blo(cB0, 1); S_Bhi(cB1, 1); S_Aq12(cA0, cA1, 1);
    asm volatile("s_waitcnt vmcnt(6)" ::: "memory");
    __builtin_amdgcn_s_barrier();

    for (int ti = start; ti < end; ti += step) {
        bool hasNext = (ti + step < end);
        if (hasNext) tilePtrs(ti + step, nA0, nA1, nB0, nB1, nm0, nn0);

        s16x8 bfr[4][2];
        for (int s = 0; s < NS; ++s) {
            const char* sb = ldsB + (s & 1) * 65536;
            int st = s + 1, st2 = s + 2;
            bool n1 = st < NS, n2 = st2 < NS;
            // ---------- phase 1 ----------
            s16x8 af[2][2];
#pragma unroll
            for (int ni = 0; ni < 4; ++ni) {
                bfr[ni][0] = *(const s16x8*)(sb + boff0 + ni * 2048);
                bfr[ni][1] = *(const s16x8*)(sb + boff1 + ni * 2048);
            }
            af[0][0] = *(const s16x8*)(sb + aoff0);
            af[0][1] = *(const s16x8*)(sb + aoff1);
            af[1][0] = *(const s16x8*)(sb + aoff0 + 2048);
            af[1][1] = *(const s16x8*)(sb + aoff1 + 2048);
            if (n1) S_Aq34(cA0, cA1, st); else if (hasNext) S_Aq34(nA0, nA1, st - NS);
            __builtin_amdgcn_s_barrier();
            __builtin_amdgcn_s_setprio(1);
#pragma unroll
            for (int mj = 0; mj < 2; ++mj)
#pragma unroll
                for (int ni = 0; ni < 4; ++ni) {
                    acc[mj][ni] = __builtin_amdgcn_mfma_f32_16x16x32_bf16(bfr[ni][0], af[mj][0], acc[mj][ni], 0, 0, 0);
                    acc[mj][ni] = __builtin_amdgcn_mfma_f32_16x16x32_bf16(bfr[ni][1], af[mj][1], acc[mj][ni], 0, 0, 0);
                }
            __builtin_amdgcn_s_setprio(0);
            __builtin_amdgcn_s_barrier();
            // ---------- phase 2 ----------
#pragma unroll
            for (int mj = 0; mj < 2; ++mj) {
                af[mj][0] = *(const s16x8*)(sb + aoff0 + (2 + mj) * 2048);
                af[mj][1] = *(const s16x8*)(sb + aoff1 + (2 + mj) * 2048);
            }
            if (n2) S_Blo(cB0, st2); else if (hasNext) S_Blo(nB0, st2 - NS);
            __builtin_amdgcn_s_barrier();
            __builtin_amdgcn_s_setprio(1);
#pragma unroll
            for (int mj = 0; mj < 2; ++mj)
#pragma unroll
                for (int ni = 0; ni < 4; ++ni) {
                    acc[2 + mj][ni] = __builtin_amdgcn_mfma_f32_16x16x32_bf16(bfr[ni][0], af[mj][0], acc[2 + mj][ni], 0, 0, 0);
                    acc[2 + mj][ni] = __builtin_amdgcn_mfma_f32_16x16x32_bf16(bfr[ni][1], af[mj][1], acc[2 + mj][ni], 0, 0, 0);
                }
            __builtin_amdgcn_s_setprio(0);
            __builtin_amdgcn_s_barrier();
            // ---------- phase 3 ----------
#pragma unroll
            for (int mj = 0; mj < 2; ++mj) {
                af[mj][0] = *(const s16x8*)(sb + aoff0 + (4 + mj) * 2048);
                af[mj][1] = *(const s16x8*)(sb + aoff1 + (4 + mj) * 2048);
            }
            if (n2) S_Bhi(cB1, st2); else if (hasNext) S_Bhi(nB1, st2 - NS);
            __builtin_amdgcn_s_barrier();
            __builtin_amdgcn_s_setprio(1);
#pragma unroll
            for (int mj = 0; mj < 2; ++mj)
#pragma unroll
                for (int ni = 0; ni < 4; ++ni) {
                    acc[4 + mj][ni] = __builtin_amdgcn_mfma_f32_16x16x32_bf16(bfr[ni][0], af[mj][0], acc[4 + mj][ni], 0, 0, 0);
                    acc[4 + mj][ni] = __builtin_amdgcn_mfma_f32_16x16x32_bf16(bfr[ni][1], af[mj][1], acc[4 + mj][ni], 0, 0, 0);
                }
            __builtin_amdgcn_s_setprio(0);
            __builtin_amdgcn_s_barrier();
            // ---------- phase 4 ----------
#pragma unroll
            for (int mj = 0; mj < 2; ++mj) {
                af[mj][0] = *(const s16x8*)(sb + aoff0 + (6 + mj) * 2048);
                af[mj][1] = *(const s16x8*)(sb + aoff1 + (6 + mj) * 2048);
            }
            if (n2) S_Aq12(cA0, cA1, st2); else if (hasNext) S_Aq12(nA0, nA1, st2 - NS);
            __builtin_amdgcn_s_barrier();
            __builtin_amdgcn_s_setprio(1);
#pragma unroll
            for (int mj = 0; mj < 2; ++mj)
#pragma unroll
                for (int ni = 0; ni < 4; ++ni) {
                    acc[6 + mj][ni] = __builtin_amdgcn_mfma_f32_16x16x32_bf16(bfr[ni][0], af[mj][0], acc[6 + mj][ni], 0, 0, 0);
                    acc[6 + mj][ni] = __builtin_amdgcn_mfma_f32_16x16x32_bf16(bfr[ni][1], af[mj][1], acc[6 + mj][ni], 0, 0, 0);
                }
            __builtin_amdgcn_s_setprio(0);
            bool staged24 = n2 || hasNext;
            bool last = (s == NS - 1) && !hasNext;
            if (!last) {
                if (staged24) asm volatile("s_waitcnt vmcnt(6)" ::: "memory");
                else          asm volatile("s_waitcnt vmcnt(0)" ::: "memory");
                __builtin_amdgcn_s_barrier();
            }
        }

        // ---- epilogue for tile ti ----
        int r_lane = lane & 15, cg = lane >> 4;
        float4 bb[4];
        if (BIAS) {
#pragma unroll
            for (int ni = 0; ni < 4; ++ni)
                bb[ni] = *(const float4*)(bias + cn0 + ngrp * 64 + ni * 16 + cg * 4);
        }
        float4 uu[4];
        float rho[8], mt[8];
        if (LNIN) {
#pragma unroll
            for (int ni = 0; ni < 4; ++ni)
                uu[ni] = *(const float4*)(uvec + cn0 + ngrp * 64 + ni * 16 + cg * 4);
#pragma unroll
            for (int mi = 0; mi < 8; ++mi) {
                int row = cm0 + mgrp * 128 + mi * 16 + r_lane;
                float2 sv = Sin[row];
                float mu = sv.x * (1.0f / 512.0f);
                float var = sv.y * (1.0f / 512.0f) - mu * mu;
                float rr = rsqrtf(var + 1e-5f);
                rho[mi] = rr; mt[mi] = mu * rr;
            }
        }
        if (BOUNCE) {
            u16* bw = bounce + wid * 1024;
            int qrow = lane >> 3, kc = lane & 7;
#pragma unroll
            for (int mi = 0; mi < 8; ++mi) {
                int rowbase = cm0 + mgrp * 128 + mi * 16;
#pragma unroll
                for (int ni = 0; ni < 4; ++ni) {
                    f32x4 v = acc[mi][ni];
                    if (LNIN) {
                        v[0] = rho[mi] * v[0] - mt[mi] * uu[ni].x + bb[ni].x;
                        v[1] = rho[mi] * v[1] - mt[mi] * uu[ni].y + bb[ni].y;
                        v[2] = rho[mi] * v[2] - mt[mi] * uu[ni].z + bb[ni].z;
                        v[3] = rho[mi] * v[3] - mt[mi] * uu[ni].w + bb[ni].w;
                    } else if (BIAS) {
                        v[0] += bb[ni].x; v[1] += bb[ni].y; v[2] += bb[ni].z; v[3] += bb[ni].w;
                    }
                    if (GELU_) {
#pragma unroll
                        for (int j = 0; j < 4; ++j) v[j] = gelu_exact(v[j]);
                    }
                    uint2 o;
                    o.x = (u32)f2bf(v[0]) | ((u32)f2bf(v[1]) << 16);
                    o.y = (u32)f2bf(v[2]) | ((u32)f2bf(v[3]) << 16);
                    int slot = (4 * ni + cg) ^ (r_lane & 14);
                    *(uint2*)(bw + r_lane * 64 + slot * 4) = o;
                    acc[mi][ni] = (f32x4){0.f, 0.f, 0.f, 0.f};
                }
                asm volatile("s_waitcnt lgkmcnt(0)" ::: "memory");
#pragma unroll
                for (int h = 0; h < 2; ++h) {
                    int rd = h * 8 + qrow;
                    int e = (2 * kc) ^ (rd & 14);
                    u32x4 t = *(const u32x4*)(bw + rd * 64 + e * 4);
                    int row = rowbase + rd;
                    int c2 = cn0 + ngrp * 64 + kc * 8;
                    u16* dst = Cb + (size_t)row * ncols + c2;
                    if (NT) __builtin_nontemporal_store(t, (u32x4*)dst);
                    else    *(u32x4*)dst = t;
                }
                asm volatile("s_waitcnt lgkmcnt(0)" ::: "memory");
            }
        } else {
#pragma unroll
            for (int mi = 0; mi < 8; ++mi) {
                int row = cm0 + mgrp * 128 + mi * 16 + r_lane;
                float s1 = 0.f, s2 = 0.f;
#pragma unroll
                for (int ni = 0; ni < 4; ++ni) {
                    int c = cn0 + ngrp * 64 + ni * 16 + cg * 4;
                    f32x4 v = acc[mi][ni];
                    if (LNIN) {
                        v[0] = rho[mi] * v[0] - mt[mi] * uu[ni].x + bb[ni].x;
                        v[1] = rho[mi] * v[1] - mt[mi] * uu[ni].y + bb[ni].y;
                        v[2] = rho[mi] * v[2] - mt[mi] * uu[ni].z + bb[ni].z;
                        v[3] = rho[mi] * v[3] - mt[mi] * uu[ni].w + bb[ni].w;
                    } else if (BIAS) {
                        v[0] += bb[ni].x; v[1] += bb[ni].y; v[2] += bb[ni].z; v[3] += bb[ni].w;
                    }
                    if (GELU_) {
#pragma unroll
                        for (int j = 0; j < 4; ++j) v[j] = gelu_exact(v[j]);
                    }
                    if (RESID) {
                        u16* px = Xbres + (size_t)row * 512 + c;
                        uint2 xv = *(uint2*)px;
                        float x0 = bflo(xv.x) + v[0];
                        float x1 = bfhi(xv.x) + v[1];
                        float x2 = bflo(xv.y) + v[2];
                        float x3 = bfhi(xv.y) + v[3];
                        uint2 o;
                        o.x = (u32)f2bf(x0) | ((u32)f2bf(x1) << 16);
                        o.y = (u32)f2bf(x2) | ((u32)f2bf(x3) << 16);
                        *(uint2*)px = o;
                        if (STATS) {
                            float r0 = bflo(o.x), r1 = bfhi(o.x), r2 = bflo(o.y), r3 = bfhi(o.y);
                            s1 += r0 + r1 + r2 + r3;
                            s2 += r0 * r0 + r1 * r1 + r2 * r2 + r3 * r3;
                        }
                    } else {
                        u32 lo = (u32)f2bf(v[0]) | ((u32)f2bf(v[1]) << 16);
                        u32 hi = (u32)f2bf(v[2]) | ((u32)f2bf(v[3]) << 16);
                        uint2 o; o.x = lo; o.y = hi;
                        *(uint2*)(Cb + (size_t)row * ncols + c) = o;
                    }
                    acc[mi][ni] = (f32x4){0.f, 0.f, 0.f, 0.f};
                }
                if (STATS) {
                    s1 += __shfl_xor(s1, 16); s2 += __shfl_xor(s2, 16);
                    s1 += __shfl_xor(s1, 32); s2 += __shfl_xor(s2, 32);
                    if (lane < 16) {
                        atomicAdd(Sout + (size_t)row * 2, s1);
                        atomicAdd(Sout + (size_t)row * 2 + 1, s2);
                    }
                }
            }
        }
        cA0 = nA0; cA1 = nA1; cB0 = nB0; cB1 = nB1; cm0 = nm0; cn0 = nn0;
    }
}

// ---------------- attention: T=4, per (sample, head) per wave ----------------
__global__ __launch_bounds__(256) void k_attn(const u16* __restrict__ QKV, u16* __restrict__ O) {
    int task = blockIdx.x * 4 + (threadIdx.x >> 6);
    int lane = threadIdx.x & 63;
    int s = task >> 2, h = task & 3;
    const u16* base = QKV + (size_t)s * 4 * 1536 + h * 128;
    float q[4][2], k[4][2], v[4][2];
#pragma unroll
    for (int t = 0; t < 4; ++t) {
        const u16* row = base + t * 1536;
        u32 uq = *(const u32*)(row + lane * 2);
        u32 uk = *(const u32*)(row + 512 + lane * 2);
        u32 uv = *(const u32*)(row + 1024 + lane * 2);
        q[t][0] = bflo(uq); q[t][1] = bfhi(uq);
        k[t][0] = bflo(uk); k[t][1] = bfhi(uk);
        v[t][0] = bflo(uv); v[t][1] = bfhi(uv);
    }
    float sc[4][4];
#pragma unroll
    for (int i = 0; i < 4; ++i)
#pragma unroll
        for (int j = 0; j < 4; ++j) {
            float p = q[i][0] * k[j][0] + q[i][1] * k[j][1];
#pragma unroll
            for (int d = 1; d < 64; d <<= 1) p += __shfl_xor(p, d);
            sc[i][j] = p * 0.08838834764831845f;  // 1/sqrt(128)
        }
    float o[4][2];
#pragma unroll
    for (int i = 0; i < 4; ++i) {
        float mx = fmaxf(fmaxf(sc[i][0], sc[i][1]), fmaxf(sc[i][2], sc[i][3]));
        float e0 = expf(sc[i][0] - mx), e1 = expf(sc[i][1] - mx);
        float e2 = expf(sc[i][2] - mx), e3 = expf(sc[i][3] - mx);
        float inv = 1.0f / (e0 + e1 + e2 + e3);
        float a0 = e0 * inv, a1 = e1 * inv, a2 = e2 * inv, a3 = e3 * inv;
        o[i][0] = a0 * v[0][0] + a1 * v[1][0] + a2 * v[2][0] + a3 * v[3][0];
        o[i][1] = a0 * v[0][1] + a1 * v[1][1] + a2 * v[2][1] + a3 * v[3][1];
    }
#pragma unroll
    for (int i = 0; i < 4; ++i) {
        u32 pk = (u32)f2bf(o[i][0]) | ((u32)f2bf(o[i][1]) << 16);
        *(u32*)(O + ((size_t)s * 4 + i) * 512 + h * 128 + lane * 2) = pk;
    }
}

// ---------------- pooling: score via qw, z, out-LN -> Zb bf16 ; wave per sample ----------------
__global__ __launch_bounds__(256) void k_pool(const u16* __restrict__ Xb, const float* __restrict__ qw,
                                              const float* __restrict__ olnw, const float* __restrict__ olnb,
                                              u16* __restrict__ Zb) {
    int s = blockIdx.x * 4 + (threadIdx.x >> 6);
    int lane = threadIdx.x & 63;
    float4 q0 = *(const float4*)(qw + lane * 8);
    float4 q1 = *(const float4*)(qw + lane * 8 + 4);
    float qv[8] = {q0.x, q0.y, q0.z, q0.w, q1.x, q1.y, q1.z, q1.w};
    u16x8 xr[4];
    float dot[4];
#pragma unroll
    for (int t = 0; t < 4; ++t) {
        xr[t] = *(const u16x8*)(Xb + ((size_t)s * 4 + t) * 512 + lane * 8);
        float p = 0.f;
#pragma unroll
        for (int j = 0; j < 8; ++j) p += qv[j] * bf2f(xr[t][j]);
#pragma unroll
        for (int d = 1; d < 64; d <<= 1) p += __shfl_xor(p, d);
        dot[t] = p * 0.044194173824159216f;  // 1/sqrt(512)
    }
    float mx = fmaxf(fmaxf(dot[0], dot[1]), fmaxf(dot[2], dot[3]));
    float e[4], se = 0.f;
#pragma unroll
    for (int t = 0; t < 4; ++t) { e[t] = expf(dot[t] - mx); se += e[t]; }
    float inv = 1.0f / se;
    float z[8] = {0, 0, 0, 0, 0, 0, 0, 0};
#pragma unroll
    for (int t = 0; t < 4; ++t) {
        float scv = e[t] * inv;
#pragma unroll
        for (int j = 0; j < 8; ++j) z[j] += scv * bf2f(xr[t][j]);
    }
    float s1 = 0.f, s2 = 0.f;
#pragma unroll
    for (int j = 0; j < 8; ++j) { s1 += z[j]; s2 += z[j] * z[j]; }
#pragma unroll
    for (int d = 1; d < 64; d <<= 1) { s1 += __shfl_xor(s1, d); s2 += __shfl_xor(s2, d); }
    float mean = s1 * (1.0f / 512.0f);
    float var  = s2 * (1.0f / 512.0f) - mean * mean;
    float rstd = rsqrtf(var + 1e-5f);
    float4 w0 = *(const float4*)(olnw + lane * 8);
    float4 w1 = *(const float4*)(olnw + lane * 8 + 4);
    float4 b0 = *(const float4*)(olnb + lane * 8);
    float4 b1 = *(const float4*)(olnb + lane * 8 + 4);
    float wv[8] = {w0.x, w0.y, w0.z, w0.w, w1.x, w1.y, w1.z, w1.w};
    float bv[8] = {b0.x, b0.y, b0.z, b0.w, b1.x, b1.y, b1.z, b1.w};
    u16x8 o;
#pragma unroll
    for (int j = 0; j < 8; ++j) o[j] = f2bf((z[j] - mean) * rstd * wv[j] + bv[j]);
    *(u16x8*)(Zb + (size_t)s * 512 + lane * 8) = o;
}

// ---------------- final: y = G(s,256) . w2 + b2 ; wave per sample ----------------
__global__ __launch_bounds__(256) void k_out2(const u16* __restrict__ G, const float* __restrict__ w2,
                                              const float* __restrict__ b2, float* __restrict__ y) {
    int s = blockIdx.x * 4 + (threadIdx.x >> 6);
    int lane = threadIdx.x & 63;
    uint2 u = *(const uint2*)(G + (size_t)s * 256 + lane * 4);
    float4 wv = *(const float4*)(w2 + lane * 4);
    float p = bflo(u.x) * wv.x + bfhi(u.x) * wv.y + bflo(u.y) * wv.z + bfhi(u.y) * wv.w;
#pragma unroll
    for (int d = 1; d < 64; d <<= 1) p += __shfl_xor(p, d);
    if (lane == 0) y[s] = p + b2[0];
}

extern "C" void kernel_launch(void* const* d_in, const int* in_sizes, int n_in,
                              void* d_out, int out_size, void* d_ws, size_t ws_size,
                              hipStream_t stream) {
    const float* x     = (const float*)d_in[0];
    const float* be    = (const float*)d_in[1];
    const float* ln1w  = (const float*)d_in[2];
    const float* ln1b  = (const float*)d_in[3];
    const float* qkvw  = (const float*)d_in[4];
    const float* qkvb  = (const float*)d_in[5];
    const float* projw = (const float*)d_in[6];
    const float* projb = (const float*)d_in[7];
    const float* ln2w  = (const float*)d_in[8];
    const float* ln2b  = (const float*)d_in[9];
    const float* f1w   = (const float*)d_in[10];
    const float* f1b   = (const float*)d_in[11];
    const float* f2w   = (const float*)d_in[12];
    const float* f2b   = (const float*)d_in[13];
    const float* poolq = (const float*)d_in[14];
    const float* poolw = (const float*)d_in[15];
    const float* olnw  = (const float*)d_in[16];
    const float* olnb  = (const float*)d_in[17];
    const float* ow1   = (const float*)d_in[18];
    const float* ob1   = (const float*)d_in[19];
    const float* ow2   = (const float*)d_in[20];
    const float* ob2   = (const float*)d_in[21];
    float* y = (float*)d_out;

    int N = in_sizes[0] / 2048;  // (N,512,4)

    char* p = (char*)d_ws;
    auto take = [&](size_t b) { char* r = p; p += (b + 255) & ~(size_t)255; return r; };
    u16* qkvWb  = (u16*)take((size_t)3145728 * 2);  // gamma-folded
    u16* projWb = (u16*)take((size_t)1048576 * 2);
    u16* f1Wb   = (u16*)take((size_t)2097152 * 2);  // gamma-folded
    u16* f2Wb   = (u16*)take((size_t)2097152 * 2);
    u16* ow1b   = (u16*)take((size_t)131072 * 2);
    float* qw   = (float*)take(512 * 4);
    float* u_qkv  = (float*)take(6144 * 4);
    float* b2_qkv = (float*)take(6144 * 4);
    float* u_f1   = (float*)take(4096 * 4);
    float* b2_f1  = (float*)take(4096 * 4);
    size_t fixedB = (size_t)(p - (char*)d_ws);

    // single chunk; halve only if ws_size forces it. per-sample: Xb 4096 +
    // Hb 4096 + QKVb 12288 + stats 64 = 20544 B
    int S = N;
    while (S > 256 && fixedB + (size_t)S * 20544 + 65536 > ws_size) S >>= 1;
    int R = S * 4;
    int TM = R / 256;

    u16* Xb    = (u16*)take((size_t)R * 512 * 2);   // persistent bf16 X
    u16* Hb    = (u16*)take((size_t)R * 512 * 2);   // attn output
    u16* QKVb  = (u16*)take((size_t)R * 1536 * 2);
    float2* S1 = (float2*)take((size_t)R * 8);      // ln1-input stats (sum, sumsq)
    float2* S2 = (float2*)take((size_t)R * 8);      // ln2-input stats
    u16* Fb  = QKVb;                                   // R x 1024 (FFN phase)
    u16* Gb  = (u16*)((char*)QKVb + (size_t)R * 512 * 2);  // S x 256 (head phase)
    u16* Zb  = Hb;

    // weight prep: gamma-folded bf16 convert, then u/b2 vectors, pool algebra
    k_cvt5<<<8320, 256, 0, stream>>>(qkvw, qkvWb, ln1w, projw, projWb,
                                     f1w, f1Wb, ln2w, f2w, f2Wb, ow1, ow1b);
    k_uv<<<2560, 256, 0, stream>>>(qkvWb, qkvw, qkvb, ln1b, u_qkv, b2_qkv,
                                   f1Wb, f1w, f1b, ln2b, u_f1, b2_f1);
    k_poolq<<<2, 256, 0, stream>>>(poolq, poolw, qw);

    auto gridFor = [](int T) { return T < 256 ? T : 256; };

    for (int c0 = 0; c0 < N; c0 += S) {
        const float* xin = x + (size_t)c0 * 2048;
        k_embed<<<S, 256, 0, stream>>>(xin, be, Xb, S1);
        for (int l = 0; l < 4; ++l) {
            { int T = TM * 6;   // QKV: A=raw Xb, LN folded (Sin=S1), zero S2; bounce+NT
              k_gemm256<true, false, false, true, true, true, false><<<gridFor(T), 512, 0, stream>>>(
                  Xb, qkvWb + (size_t)l * 786432, b2_qkv + l * 1536, QKVb, nullptr,
                  S1, (float*)S2, u_qkv + l * 1536, 512, 1536, 6, T, R); }
            k_attn<<<S, 256, 0, stream>>>(QKVb, Hb);
            { int T = TM * 2;   // proj: resid RMW + stats -> S2
              k_gemm256<true, false, true, false, false, false, true><<<gridFor(T), 512, 0, stream>>>(
                  Hb, projWb + (size_t)l * 262144, projb + l * 512, nullptr, Xb,
                  nullptr, (float*)S2, nullptr, 512, 512, 2, T, R); }
            { int T = TM * 4;   // ffn1: A=raw Xb, LN folded (Sin=S2), zero S1; gelu
              k_gemm256<true, true, false, false, false, true, false><<<gridFor(T), 512, 0, stream>>>(
                  Xb, f1Wb + (size_t)l * 524288, b2_f1 + l * 1024, Fb, nullptr,
                  S2, (float*)S1, u_f1 + l * 1024, 512, 1024, 4, T, R); }
            if (l < 3) {        // ffn2: resid RMW + stats -> S1 (next layer's ln1)
                int T = TM * 2;
                k_gemm256<true, false, true, false, false, false, true><<<gridFor(T), 512, 0, stream>>>(
                    Fb, f2Wb + (size_t)l * 524288, f2b + l * 512, nullptr, Xb,
                    nullptr, (float*)S1, nullptr, 1024, 512, 2, T, R);
            } else {            // last ffn2: plain resid (no more LN consumers)
                int T = TM * 2;
                k_gemm256<true, false, true, false, false, false, false><<<gridFor(T), 512, 0, stream>>>(
                    Fb, f2Wb + (size_t)l * 524288, f2b + l * 512, nullptr, Xb,
                    nullptr, nullptr, nullptr, 1024, 512, 2, T, R);
            }
        }
        k_pool<<<S / 4, 256, 0, stream>>>(Xb, qw, olnw, olnb, Zb);
        { int T = S / 256;
          k_gemm256<true, true, false, false, false, false, false><<<gridFor(T), 512, 0, stream>>>(
              Zb, ow1b, ob1, Gb, nullptr, nullptr, nullptr, nullptr, 512, 256, 1, T, R); }
        k_out2<<<S / 4, 256, 0, stream>>>(Gb, ow2, ob2, y + c0);
    }
    (void)n_in; (void)out_size; (void)ws_size;
}